// Round 10
// baseline (553.965 us; speedup 1.0000x reference)
//
#include <hip/hip_runtime.h>

#define DD 1024
#define NHH 16
#define HDD 64
#define BB 2
#define LL 2048
#define MM (BB*LL)          // 4096 rows
#define HG 256
#define HN 128

#define LOG_FAST 0.48121182f   // ln((1+sqrt(5))/2)
#define LOG_SLOW 7.3889461f    // ln(1618.0)
#define LOG_GLU  9.6915312f    // ln(16180.0)
#define SCL 0.18033688f        // 0.125 * log2(e); scores kept in (QK + 8*gb) raw domain

typedef __attribute__((ext_vector_type(8))) short short8;
typedef __attribute__((ext_vector_type(4))) float f32x4;

__device__ __forceinline__ float gelu_f(float x) {
    return 0.5f * x * (1.0f + erff(x * 0.70710678f));
}

__device__ __forceinline__ ushort f2b(float x) {
    unsigned u = __float_as_uint(x);
    unsigned r = (u + 0x7FFFu + ((u >> 16) & 1u)) >> 16;
    return (ushort)r;
}

__device__ __forceinline__ float b2f(ushort x) {
    return __uint_as_float(((unsigned)x) << 16);
}

__device__ __forceinline__ void gl_lds16(const ushort* g, ushort* l) {
    __builtin_amdgcn_global_load_lds(
        (const __attribute__((address_space(1))) unsigned int*)g,
        (__attribute__((address_space(3))) unsigned int*)l, 16, 0, 0);
}

// ushort offset of swizzled 16B chunk within a 64x64 bf16 tile
#define SWZC(row, c8) (((((row) << 3) | ((c8) ^ ((row) & 7)))) << 3)

// Stage a 64x64 bf16 tile (row-major, rstride in elements) into LDS with XOR swizzle.
// 2 VMEM (global_load_lds) ops per lane per call.
__device__ __forceinline__ void stage_tile(const ushort* gsrc, int rstride,
                                           ushort* lds, int tid) {
    int wid = tid >> 6;
#pragma unroll
    for (int r = 0; r < 2; ++r) {
        int c = r * 256 + tid;
        int row = c >> 3;
        int c8 = (c & 7) ^ (row & 7);
        gl_lds16(gsrc + (size_t)row * rstride + c8 * 8,
                 lds + (size_t)(r * 256 + wid * 64) * 8);
    }
}

// ---------------- parallel causal cumulative mean pool (+ z->bf16 fused) ----------------
#define LCH 128
#define NCH 16
__global__ void pool_scan1(const float* __restrict__ z, float* __restrict__ part,
                           float* __restrict__ ctot, ushort* __restrict__ zb) {
    int ch = blockIdx.x, dg = blockIdx.y, b = blockIdx.z;
    int d = dg * 256 + threadIdx.x;
    size_t base = ((size_t)b * LL + ch * LCH) * DD + d;
    const float* zp = z + base;
    float* pp = part + base;
    ushort* zo = zb + base;
    float s = 0.f;
    for (int t = 0; t < LCH; ++t) {
        float v = zp[(size_t)t * DD];
        s += v;
        pp[(size_t)t * DD] = s;
        zo[(size_t)t * DD] = f2b(v);
    }
    ctot[((size_t)b * NCH + ch) * DD + d] = s;
}
__global__ void pool_scan2(const float* __restrict__ part, const float* __restrict__ ctot,
                           ushort* __restrict__ poolb) {
    int ch = blockIdx.x, dg = blockIdx.y, b = blockIdx.z;
    int d = dg * 256 + threadIdx.x;
    float off = 0.f;
    for (int c = 0; c < ch; ++c) off += ctot[((size_t)b * NCH + c) * DD + d];
    int t0 = ch * LCH;
    size_t base = ((size_t)b * LL + t0) * DD + d;
    const float* pp = part + base;
    ushort* po = poolb + base;
    for (int t = 0; t < LCH; ++t) {
        po[(size_t)t * DD] = f2b((pp[(size_t)t * DD] + off) / (float)(t0 + t + 1));
    }
}

// ---------------- weight transpose converters ----------------
// four square 1024x1024 weights -> transposed bf16 slots (z selects)
__global__ void f2bT4_kernel(const float* __restrict__ W0, const float* __restrict__ W1,
                             const float* __restrict__ W2, const float* __restrict__ W3,
                             ushort* __restrict__ Wt) {
    const float* W = blockIdx.z == 0 ? W0 : (blockIdx.z == 1 ? W1 :
                     (blockIdx.z == 2 ? W2 : W3));
    ushort* dst = Wt + (size_t)blockIdx.z * 1024 * 1024;
    __shared__ float t[32][33];
    int n0 = blockIdx.x * 32, k0 = blockIdx.y * 32;
    int tx = threadIdx.x & 31, ty = threadIdx.x >> 5;
#pragma unroll
    for (int j = 0; j < 4; ++j)
        t[ty + j * 8][tx] = W[(size_t)(k0 + ty + j * 8) * 1024 + n0 + tx];
    __syncthreads();
#pragma unroll
    for (int j = 0; j < 4; ++j)
        dst[(size_t)(n0 + ty + j * 8) * 1024 + k0 + tx] = f2b(t[tx][ty + j * 8]);
}

// rg_w1 (1024x256) and nu_w1 (1024x128) -> transposed bf16 (z selects)
__global__ void f2bT_rgnu(const float* __restrict__ Wrg, const float* __restrict__ Wnu,
                          ushort* __restrict__ WtRG, ushort* __restrict__ WtNU) {
    int zc = blockIdx.z;
    if (zc == 1 && blockIdx.x >= 4) return;
    const float* W = zc == 0 ? Wrg : Wnu;
    ushort* dst = zc == 0 ? WtRG : WtNU;
    int Ndim = zc == 0 ? HG : HN;
    __shared__ float t[32][33];
    int n0 = blockIdx.x * 32, k0 = blockIdx.y * 32;
    int tx = threadIdx.x & 31, ty = threadIdx.x >> 5;
#pragma unroll
    for (int j = 0; j < 4; ++j)
        t[ty + j * 8][tx] = W[(size_t)(k0 + ty + j * 8) * Ndim + n0 + tx];
    __syncthreads();
#pragma unroll
    for (int j = 0; j < 4; ++j)
        dst[(size_t)(n0 + ty + j * 8) * 1024 + k0 + tx] = f2b(t[tx][ty + j * 8]);
}

// three square 1024x1024 weights -> transposed bf16 slots
__global__ void f2bT3_kernel(const float* __restrict__ W0, const float* __restrict__ W1,
                             const float* __restrict__ W2, ushort* __restrict__ Wt) {
    const float* W = blockIdx.z == 0 ? W0 : (blockIdx.z == 1 ? W1 : W2);
    ushort* dst = Wt + (size_t)blockIdx.z * 1024 * 1024;
    __shared__ float t[32][33];
    int n0 = blockIdx.x * 32, k0 = blockIdx.y * 32;
    int tx = threadIdx.x & 31, ty = threadIdx.x >> 5;
#pragma unroll
    for (int j = 0; j < 4; ++j)
        t[ty + j * 8][tx] = W[(size_t)(k0 + ty + j * 8) * 1024 + n0 + tx];
    __syncthreads();
#pragma unroll
    for (int j = 0; j < 4; ++j)
        dst[(size_t)(n0 + ty + j * 8) * 1024 + k0 + tx] = f2b(t[tx][ty + j * 8]);
}

// ---------------- fused 4-slice GEMM, BK=64 (32 MFMAs per barrier drain) -------------
// zid 0..2: C = Az @ Wt[zid]^T + bias[zid] (fp32), zid==1 also emits bf16 K16r.
// zid 3:    gk16 = f2b(Ap @ Wt[3]^T)  (bf16, no bias).
__global__ __launch_bounds__(256) void gemm_mfma4(
        const ushort* __restrict__ Az, const ushort* __restrict__ Ap,
        const ushort* __restrict__ Wt,
        const float* __restrict__ b0, const float* __restrict__ b1,
        const float* __restrict__ b2, float* __restrict__ C,
        ushort* __restrict__ K16r, ushort* __restrict__ gk16) {
    int zid = blockIdx.z;
    const ushort* A = (zid < 3) ? Az : Ap;
    const ushort* W = Wt + (size_t)zid * 1024 * 1024;
    __shared__ ushort As[8192];
    __shared__ ushort Bs[8192];
    int tid = threadIdx.x;
    int wid = tid >> 6, lane = tid & 63;
    int n0 = blockIdx.x * 128, m0 = blockIdx.y * 128;
    int wm = wid >> 1, wn = wid & 1;
    int quad = lane >> 4, l16 = lane & 15;

    f32x4 acc[4][4];
#pragma unroll
    for (int mi = 0; mi < 4; ++mi)
#pragma unroll
        for (int ni = 0; ni < 4; ++ni) acc[mi][ni] = (f32x4){0.f, 0.f, 0.f, 0.f};

    int c0 = wid * 128 + lane;
    int c1 = c0 + 64;
    const ushort* Ag0 = A + (size_t)(m0 + (c0 & 127)) * 1024 + (c0 >> 7) * 8;
    const ushort* Ag1 = A + (size_t)(m0 + (c1 & 127)) * 1024 + (c1 >> 7) * 8;
    const ushort* Bg0 = W + (size_t)(n0 + (c0 & 127)) * 1024 + (c0 >> 7) * 8;
    const ushort* Bg1 = W + (size_t)(n0 + (c1 & 127)) * 1024 + (c1 >> 7) * 8;
    ushort* Al0 = As + wid * 1024;
    ushort* Al1 = As + wid * 1024 + 512;
    ushort* Bl0 = Bs + wid * 1024;
    ushort* Bl1 = Bs + wid * 1024 + 512;

    const ushort* a_rd = &As[(quad * 128 + wm * 64 + l16) * 8];
    const ushort* b_rd = &Bs[(quad * 128 + wn * 64 + l16) * 8];

    for (int kb = 0; kb < 1024; kb += 64) {
        gl_lds16(Ag0 + kb, Al0);
        gl_lds16(Ag1 + kb, Al1);
        gl_lds16(Bg0 + kb, Bl0);
        gl_lds16(Bg1 + kb, Bl1);
        gl_lds16(Ag0 + kb + 32, Al0 + 4096);
        gl_lds16(Ag1 + kb + 32, Al1 + 4096);
        gl_lds16(Bg0 + kb + 32, Bl0 + 4096);
        gl_lds16(Bg1 + kb + 32, Bl1 + 4096);
        __syncthreads();
#pragma unroll
        for (int ks = 0; ks < 2; ++ks) {
            short8 af[4], bf[4];
#pragma unroll
            for (int mi = 0; mi < 4; ++mi)
                af[mi] = *(const short8*)(a_rd + ks * 4096 + mi * 16 * 8);
#pragma unroll
            for (int ni = 0; ni < 4; ++ni)
                bf[ni] = *(const short8*)(b_rd + ks * 4096 + ni * 16 * 8);
#pragma unroll
            for (int mi = 0; mi < 4; ++mi)
#pragma unroll
                for (int ni = 0; ni < 4; ++ni)
                    acc[mi][ni] = __builtin_amdgcn_mfma_f32_16x16x32_bf16(
                        af[mi], bf[ni], acc[mi][ni], 0, 0, 0);
        }
        __syncthreads();
    }
    int bcol[4];
#pragma unroll
    for (int ni = 0; ni < 4; ++ni) bcol[ni] = n0 + wn * 64 + ni * 16 + l16;

    if (zid == 3) {
#pragma unroll
        for (int mi = 0; mi < 4; ++mi) {
#pragma unroll
            for (int r = 0; r < 4; ++r) {
                int row = m0 + wm * 64 + mi * 16 + quad * 4 + r;
                ushort* Cp = gk16 + (size_t)row * 1024;
#pragma unroll
                for (int ni = 0; ni < 4; ++ni)
                    Cp[bcol[ni]] = f2b(acc[mi][ni][r]);
            }
        }
        return;
    }
    const float* bias = zid == 0 ? b0 : (zid == 1 ? b1 : b2);
    float* Cz = C + (size_t)zid * (size_t)MM * DD;
    float bval[4];
#pragma unroll
    for (int ni = 0; ni < 4; ++ni) bval[ni] = bias[bcol[ni]];
    bool doK = (zid == 1) && (K16r != nullptr);
#pragma unroll
    for (int mi = 0; mi < 4; ++mi) {
#pragma unroll
        for (int r = 0; r < 4; ++r) {
            int row = m0 + wm * 64 + mi * 16 + quad * 4 + r;
            float* Cp = Cz + (size_t)row * 1024;
            ushort* Kp = K16r + (size_t)row * 1024;
#pragma unroll
            for (int ni = 0; ni < 4; ++ni) {
                float v = acc[mi][ni][r] + bval[ni];
                Cp[bcol[ni]] = v;
                if (doK) Kp[bcol[ni]] = f2b(v);
            }
        }
    }
}

// ---------------- split-K GEMM for mlp_out (BK=64): two K-halves to partials ---------
__global__ __launch_bounds__(256) void gemm_splitk(
        const ushort* __restrict__ A, const ushort* __restrict__ Wt,
        float* __restrict__ C0, float* __restrict__ C1) {
    int zid = blockIdx.z;
    float* C = zid ? C1 : C0;
    int kbase = zid * 512;
    __shared__ ushort As[8192];
    __shared__ ushort Bs[8192];
    int tid = threadIdx.x;
    int wid = tid >> 6, lane = tid & 63;
    int n0 = blockIdx.x * 128, m0 = blockIdx.y * 128;
    int wm = wid >> 1, wn = wid & 1;
    int quad = lane >> 4, l16 = lane & 15;

    f32x4 acc[4][4];
#pragma unroll
    for (int mi = 0; mi < 4; ++mi)
#pragma unroll
        for (int ni = 0; ni < 4; ++ni) acc[mi][ni] = (f32x4){0.f, 0.f, 0.f, 0.f};

    int c0 = wid * 128 + lane;
    int c1 = c0 + 64;
    const ushort* Ag0 = A + (size_t)(m0 + (c0 & 127)) * 1024 + (c0 >> 7) * 8 + kbase;
    const ushort* Ag1 = A + (size_t)(m0 + (c1 & 127)) * 1024 + (c1 >> 7) * 8 + kbase;
    const ushort* Bg0 = Wt + (size_t)(n0 + (c0 & 127)) * 1024 + (c0 >> 7) * 8 + kbase;
    const ushort* Bg1 = Wt + (size_t)(n0 + (c1 & 127)) * 1024 + (c1 >> 7) * 8 + kbase;
    ushort* Al0 = As + wid * 1024;
    ushort* Al1 = As + wid * 1024 + 512;
    ushort* Bl0 = Bs + wid * 1024;
    ushort* Bl1 = Bs + wid * 1024 + 512;

    const ushort* a_rd = &As[(quad * 128 + wm * 64 + l16) * 8];
    const ushort* b_rd = &Bs[(quad * 128 + wn * 64 + l16) * 8];

    for (int kb = 0; kb < 512; kb += 64) {
        gl_lds16(Ag0 + kb, Al0);
        gl_lds16(Ag1 + kb, Al1);
        gl_lds16(Bg0 + kb, Bl0);
        gl_lds16(Bg1 + kb, Bl1);
        gl_lds16(Ag0 + kb + 32, Al0 + 4096);
        gl_lds16(Ag1 + kb + 32, Al1 + 4096);
        gl_lds16(Bg0 + kb + 32, Bl0 + 4096);
        gl_lds16(Bg1 + kb + 32, Bl1 + 4096);
        __syncthreads();
#pragma unroll
        for (int ks = 0; ks < 2; ++ks) {
            short8 af[4], bf[4];
#pragma unroll
            for (int mi = 0; mi < 4; ++mi)
                af[mi] = *(const short8*)(a_rd + ks * 4096 + mi * 16 * 8);
#pragma unroll
            for (int ni = 0; ni < 4; ++ni)
                bf[ni] = *(const short8*)(b_rd + ks * 4096 + ni * 16 * 8);
#pragma unroll
            for (int mi = 0; mi < 4; ++mi)
#pragma unroll
                for (int ni = 0; ni < 4; ++ni)
                    acc[mi][ni] = __builtin_amdgcn_mfma_f32_16x16x32_bf16(
                        af[mi], bf[ni], acc[mi][ni], 0, 0, 0);
        }
        __syncthreads();
    }
#pragma unroll
    for (int mi = 0; mi < 4; ++mi) {
#pragma unroll
        for (int r = 0; r < 4; ++r) {
            int row = m0 + wm * 64 + mi * 16 + quad * 4 + r;
            float* Cp = C + (size_t)row * 1024;
#pragma unroll
            for (int ni = 0; ni < 4; ++ni)
                Cp[n0 + wn * 64 + ni * 16 + l16] = acc[mi][ni][r];
        }
    }
}

// ---------------- fused H1/N1 GEMM (BK=64): x<2 -> H1 (256), else N1 (128) -----------
__global__ __launch_bounds__(256) void gemm_gates(
        const ushort* __restrict__ A, const ushort* __restrict__ WtRG,
        const ushort* __restrict__ WtNU, const float* __restrict__ rg_b1,
        const float* __restrict__ nu_b1, float* __restrict__ H1,
        float* __restrict__ N1) {
    int bx = blockIdx.x;
    bool isH = bx < 2;
    const ushort* Wt = isH ? WtRG : WtNU;
    const float* bias = isH ? rg_b1 : nu_b1;
    float* C = isH ? H1 : N1;
    int Ndim = isH ? HG : HN;
    int n0 = isH ? bx * 128 : 0;
    int m0 = blockIdx.y * 128;
    __shared__ ushort As[8192];
    __shared__ ushort Bs[8192];
    int tid = threadIdx.x;
    int wid = tid >> 6, lane = tid & 63;
    int wm = wid >> 1, wn = wid & 1;
    int quad = lane >> 4, l16 = lane & 15;

    f32x4 acc[4][4];
#pragma unroll
    for (int mi = 0; mi < 4; ++mi)
#pragma unroll
        for (int ni = 0; ni < 4; ++ni) acc[mi][ni] = (f32x4){0.f, 0.f, 0.f, 0.f};

    int c0 = wid * 128 + lane;
    int c1 = c0 + 64;
    const ushort* Ag0 = A + (size_t)(m0 + (c0 & 127)) * 1024 + (c0 >> 7) * 8;
    const ushort* Ag1 = A + (size_t)(m0 + (c1 & 127)) * 1024 + (c1 >> 7) * 8;
    const ushort* Bg0 = Wt + (size_t)(n0 + (c0 & 127)) * 1024 + (c0 >> 7) * 8;
    const ushort* Bg1 = Wt + (size_t)(n0 + (c1 & 127)) * 1024 + (c1 >> 7) * 8;
    ushort* Al0 = As + wid * 1024;
    ushort* Al1 = As + wid * 1024 + 512;
    ushort* Bl0 = Bs + wid * 1024;
    ushort* Bl1 = Bs + wid * 1024 + 512;

    const ushort* a_rd = &As[(quad * 128 + wm * 64 + l16) * 8];
    const ushort* b_rd = &Bs[(quad * 128 + wn * 64 + l16) * 8];

    for (int kb = 0; kb < 1024; kb += 64) {
        gl_lds16(Ag0 + kb, Al0);
        gl_lds16(Ag1 + kb, Al1);
        gl_lds16(Bg0 + kb, Bl0);
        gl_lds16(Bg1 + kb, Bl1);
        gl_lds16(Ag0 + kb + 32, Al0 + 4096);
        gl_lds16(Ag1 + kb + 32, Al1 + 4096);
        gl_lds16(Bg0 + kb + 32, Bl0 + 4096);
        gl_lds16(Bg1 + kb + 32, Bl1 + 4096);
        __syncthreads();
#pragma unroll
        for (int ks = 0; ks < 2; ++ks) {
            short8 af[4], bf[4];
#pragma unroll
            for (int mi = 0; mi < 4; ++mi)
                af[mi] = *(const short8*)(a_rd + ks * 4096 + mi * 16 * 8);
#pragma unroll
            for (int ni = 0; ni < 4; ++ni)
                bf[ni] = *(const short8*)(b_rd + ks * 4096 + ni * 16 * 8);
#pragma unroll
            for (int mi = 0; mi < 4; ++mi)
#pragma unroll
                for (int ni = 0; ni < 4; ++ni)
                    acc[mi][ni] = __builtin_amdgcn_mfma_f32_16x16x32_bf16(
                        af[mi], bf[ni], acc[mi][ni], 0, 0, 0);
        }
        __syncthreads();
    }
    int bcol[4];
    float bval[4];
#pragma unroll
    for (int ni = 0; ni < 4; ++ni) {
        bcol[ni] = n0 + wn * 64 + ni * 16 + l16;
        bval[ni] = bias[bcol[ni]];
    }
#pragma unroll
    for (int mi = 0; mi < 4; ++mi) {
#pragma unroll
        for (int r = 0; r < 4; ++r) {
            int row = m0 + wm * 64 + mi * 16 + quad * 4 + r;
            float* Cp = C + (size_t)row * Ndim;
#pragma unroll
            for (int ni = 0; ni < 4; ++ni)
                Cp[bcol[ni]] = acc[mi][ni][r] + bval[ni];
        }
    }
}

// ---------------- gb8 (bf16, BK=64) = 8*tanh(gamma)/32 * gk16 @ K16r^T ---------------
// pi-permuted output: value for k-local (nt*16+l16) stored at position l16*4+nt.
__global__ __launch_bounds__(256) void gb_mfma(
        const ushort* __restrict__ gk16, const ushort* __restrict__ K16r,
        const float* __restrict__ gamma, ushort* __restrict__ gb) {
    int lt = blockIdx.x >> 4, mt = blockIdx.x & 15;
    if (mt > lt) return;
    int b = blockIdx.y;
    __shared__ ushort As[8192];
    __shared__ ushort Bs[8192];
    int tid = threadIdx.x;
    int wid = tid >> 6, lane = tid & 63;
    int l0 = lt * 128, m0 = mt * 128;
    int wm = wid >> 1, wn = wid & 1;
    int quad = lane >> 4, l16 = lane & 15;

    f32x4 acc[4][4];
#pragma unroll
    for (int mi = 0; mi < 4; ++mi)
#pragma unroll
        for (int ni = 0; ni < 4; ++ni) acc[mi][ni] = (f32x4){0.f, 0.f, 0.f, 0.f};

    int c0 = wid * 128 + lane;
    int c1 = c0 + 64;
    const ushort* Ag0 = gk16 + ((size_t)b * LL + l0 + (c0 & 127)) * 1024 + (c0 >> 7) * 8;
    const ushort* Ag1 = gk16 + ((size_t)b * LL + l0 + (c1 & 127)) * 1024 + (c1 >> 7) * 8;
    const ushort* Bg0 = K16r + ((size_t)b * LL + m0 + (c0 & 127)) * 1024 + (c0 >> 7) * 8;
    const ushort* Bg1 = K16r + ((size_t)b * LL + m0 + (c1 & 127)) * 1024 + (c1 >> 7) * 8;
    ushort* Al0 = As + wid * 1024;
    ushort* Al1 = As + wid * 1024 + 512;
    ushort* Bl0 = Bs + wid * 1024;
    ushort* Bl1 = Bs + wid * 1024 + 512;

    const ushort* a_rd = &As[(quad * 128 + wm * 64 + l16) * 8];
    const ushort* b_rd = &Bs[(quad * 128 + wn * 64 + l16) * 8];

    for (int kb = 0; kb < 1024; kb += 64) {
        gl_lds16(Ag0 + kb, Al0);
        gl_lds16(Ag1 + kb, Al1);
        gl_lds16(Bg0 + kb, Bl0);
        gl_lds16(Bg1 + kb, Bl1);
        gl_lds16(Ag0 + kb + 32, Al0 + 4096);
        gl_lds16(Ag1 + kb + 32, Al1 + 4096);
        gl_lds16(Bg0 + kb + 32, Bl0 + 4096);
        gl_lds16(Bg1 + kb + 32, Bl1 + 4096);
        __syncthreads();
#pragma unroll
        for (int ks = 0; ks < 2; ++ks) {
            short8 af[4], bf[4];
#pragma unroll
            for (int mi = 0; mi < 4; ++mi)
                af[mi] = *(const short8*)(a_rd + ks * 4096 + mi * 16 * 8);
#pragma unroll
            for (int ni = 0; ni < 4; ++ni)
                bf[ni] = *(const short8*)(b_rd + ks * 4096 + ni * 16 * 8);
#pragma unroll
            for (int mi = 0; mi < 4; ++mi)
#pragma unroll
                for (int ni = 0; ni < 4; ++ni)
                    acc[mi][ni] = __builtin_amdgcn_mfma_f32_16x16x32_bf16(
                        af[mi], bf[ni], acc[mi][ni], 0, 0, 0);
        }
        __syncthreads();
    }
    float scale = tanhf(gamma[0]) * 0.25f;   // (1/32) * 8
#pragma unroll
    for (int mi = 0; mi < 4; ++mi) {
#pragma unroll
        for (int r = 0; r < 4; ++r) {
            int row = l0 + wm * 64 + mi * 16 + quad * 4 + r;
            ushort* Cp = gb + ((size_t)b * LL + row) * LL;
            ushort4 o;
            o.x = f2b(acc[mi][0][r] * scale);
            o.y = f2b(acc[mi][1][r] * scale);
            o.z = f2b(acc[mi][2][r] * scale);
            o.w = f2b(acc[mi][3][r] * scale);
            *(ushort4*)(Cp + m0 + wn * 64 + l16 * 4) = o;
        }
    }
}

// ---------------- fused gate + nu finisher ----------------
__global__ __launch_bounds__(256) void gatenu_fin(
        const float* __restrict__ H1, const float* __restrict__ N1,
        const float* __restrict__ rg_w2, const float* __restrict__ rg_b2,
        const float* __restrict__ nu_w2, const float* __restrict__ nu_b2,
        const float* __restrict__ nu_diff, const float* __restrict__ nu_adv,
        float* __restrict__ gate, float* __restrict__ nub) {
    int row = blockIdx.x, tid = threadIdx.x;
    float gv = gelu_f(H1[(size_t)row * HG + tid]) * rg_w2[tid];
    float nv = (tid < HN) ? tanhf(N1[(size_t)row * HN + tid]) * nu_w2[tid] : 0.f;
    for (int off = 32; off; off >>= 1) {
        gv += __shfl_down(gv, off);
        nv += __shfl_down(nv, off);
    }
    __shared__ float pg[4], pn[4];
    if ((tid & 63) == 0) { pg[tid >> 6] = gv; pn[tid >> 6] = nv; }
    __syncthreads();
    if (tid == 0) {
        float ga = pg[0] + pg[1] + pg[2] + pg[3] + rg_b2[0];
        gate[row] = 1.f / (1.f + expf(-ga));
        float na = pn[0] + pn[1] + pn[2] + pn[3] + nu_b2[0];
        nub[row] = fabsf(nu_diff[0]) + tanhf(na) * fabsf(nu_adv[0]);
    }
}

// ---------------- gated dual-base RoPE on Q and K -> bf16 head-blocked [b,h,L,64] -------
__global__ void rope_qk_bf16(const float* __restrict__ Q, const float* __restrict__ K,
                             const float* __restrict__ gate,
                             ushort* __restrict__ Q16, ushort* __restrict__ K16) {
    int idx = blockIdx.x * 256 + threadIdx.x;   // over MM*512
    int row = idx >> 9;
    int i = idx & 511;
    int b = row >> 11, t = row & (LL - 1);
    float g = gate[row];
    float fi = (float)i * (1.0f / 512.0f);
    float tf = (float)t;
    float af = tf * expf(-fi * LOG_FAST);
    float as = tf * expf(-fi * LOG_SLOW);
    float c = g * cosf(af) + (1.f - g) * cosf(as);
    float s = g * sinf(af) + (1.f - g) * sinf(as);
    size_t base = (size_t)row * DD;
    float x = Q[base + i], y = Q[base + 512 + i];
    float q1 = x * c - y * s, q2 = y * c + x * s;
    x = K[base + i]; y = K[base + 512 + i];
    float k1 = x * c - y * s, k2 = y * c + x * s;
    int h1 = i >> 6, d1 = i & 63;
    size_t o1 = ((size_t)(b * 16 + h1) * LL + t) * 64 + d1;
    size_t o2 = ((size_t)(b * 16 + 8 + h1) * LL + t) * 64 + d1;
    Q16[o1] = f2b(q1); Q16[o2] = f2b(q2);
    K16[o1] = f2b(k1); K16[o2] = f2b(k2);
}

// ---------------- V fp32 [b*L,1024] -> V^T bf16 [b,h,64,L] ----------------
__global__ __launch_bounds__(256) void vt16_kernel(const float* __restrict__ V,
                                                   ushort* __restrict__ VT) {
    __shared__ ushort t[64][72];
    int lb = blockIdx.x, hb = blockIdx.y, b = blockIdx.z;
    int tid = threadIdx.x;
    {
        int l = tid >> 2, c0 = (tid & 3) * 16;
        const float* Vp = V + ((size_t)(b * LL) + lb * 64 + l) * DD + hb * 64 + c0;
#pragma unroll
        for (int j = 0; j < 4; ++j) {
            float4 v = *(const float4*)(Vp + j * 4);
            t[l][c0 + j * 4 + 0] = f2b(v.x);
            t[l][c0 + j * 4 + 1] = f2b(v.y);
            t[l][c0 + j * 4 + 2] = f2b(v.z);
            t[l][c0 + j * 4 + 3] = f2b(v.w);
        }
    }
    __syncthreads();
    {
        int d = tid >> 2, l0 = (tid & 3) * 16;
        ushort tmp[16];
#pragma unroll
        for (int j = 0; j < 16; ++j) tmp[j] = t[l0 + j][d];
        ushort* Op = VT + ((size_t)((b * 16 + hb) * 64) + d) * LL + lb * 64 + l0;
        *(ushort4*)(Op + 0)  = *(ushort4*)&tmp[0];
        *(ushort4*)(Op + 4)  = *(ushort4*)&tmp[4];
        *(ushort4*)(Op + 8)  = *(ushort4*)&tmp[8];
        *(ushort4*)(Op + 12) = *(ushort4*)&tmp[12];
    }
}

// ---------------- fixed-base RoPE for GLU branch, bf16 output ----------------
__global__ void rope_glu_b16(const float* __restrict__ z, ushort* __restrict__ zg) {
    int idx = blockIdx.x * 256 + threadIdx.x;
    int row = idx >> 9;
    int i = idx & 511;
    int t = row & (LL - 1);
    float fi = (float)i * (1.0f / 512.0f);
    float ag = (float)t * expf(-fi * LOG_GLU);
    float c = cosf(ag), s = sinf(ag);
    size_t base = (size_t)row * DD;
    float x = z[base + i], y = z[base + 512 + i];
    zg[base + i]       = f2b(x * c - y * s);
    zg[base + 512 + i] = f2b(y * c + x * s);
}

// ---------------- MFMA flash attention (FROZEN, round-8 measured 68.5us) -------------
__global__ __launch_bounds__(256, 4) void attn_flash_mfma(
        const ushort* __restrict__ Q16, const ushort* __restrict__ K16,
        const ushort* __restrict__ VT16, const ushort* __restrict__ gb16,
        float* __restrict__ attn_out, float* __restrict__ stats) {
    int h = blockIdx.x;
    int yy = blockIdx.y;
    int b = blockIdx.z;
    int qt = (yy < 16) ? yy : (47 - yy);
    int q0 = qt * 64;
    __shared__ ushort Ks0[4096];
    __shared__ ushort Vs0[4096];
    __shared__ ushort Ks1[4096];
    __shared__ ushort Vs1[4096];
    __shared__ ushort Ps[4096];        // per-wave 16x64 swizzled P (wid*1024)
    int tid = threadIdx.x, wid = tid >> 6, lane = tid & 63;
    int quad = lane >> 4, l16 = lane & 15;
    const ushort* Qg = Q16 + ((size_t)(b * 16 + h) * LL) * 64;
    const ushort* Kg = K16 + ((size_t)(b * 16 + h) * LL) * 64;
    const ushort* Vg = VT16 + ((size_t)(b * 16 + h) * 64) * LL;
    const ushort* gbB = gb16 + (size_t)b * LL * LL;
    float* stB = stats + ((size_t)(b * 16 + h) * LL) * 2;
    int qrow = wid * 16 + quad * 4;
    ushort* Pw = Ps + wid * 1024;

    short ov = (l16 == 0) ? (short)0x3F80 : (short)0;
    short8 onesf = {ov, ov, ov, ov, ov, ov, ov, ov};

    short8 qf[2];
    {
        const ushort* qp = Qg + (size_t)(q0 + wid * 16 + l16) * 64 + quad * 8;
        qf[0] = *(const short8*)(qp);
        qf[1] = *(const short8*)(qp + 32);
    }
    stage_tile(Kg, 64, Ks0, tid);
    stage_tile(Vg, LL, Vs0, tid);
    __syncthreads();

    f32x4 ofr[5];   // [0..3]=O cols, [4]=row-sum l (lives in l16==0 lanes)
    float m_r[4];
#pragma unroll
    for (int nt = 0; nt < 5; ++nt) ofr[nt] = (f32x4){0.f, 0.f, 0.f, 0.f};
#pragma unroll
    for (int r = 0; r < 4; ++r) m_r[r] = -3e38f;

#define FLASH_PHASE(KC, VC, KN, VN, T) do {                                       \
    int k0_ = (T) * 64;                                                           \
    if ((T) + 1 <= qt) {                                                          \
        stage_tile(Kg + (size_t)(k0_ + 64) * 64, 64, (KN), tid);                  \
        stage_tile(Vg + (k0_ + 64), LL, (VN), tid);                               \
    }                                                                             \
    f32x4 sf_[4];                                                                 \
    _Pragma("unroll")                                                             \
    for (int r = 0; r < 4; ++r) {                                                 \
        ushort4 g4_ = *(const ushort4*)(gbB + (size_t)(q0 + qrow + r) * LL + k0_ + l16 * 4); \
        sf_[0][r] = b2f(g4_.x); sf_[1][r] = b2f(g4_.y);                           \
        sf_[2][r] = b2f(g4_.z); sf_[3][r] = b2f(g4_.w);                           \
    }                                                                             \
    _Pragma("unroll")                                                             \
    for (int ks = 0; ks < 2; ++ks)                                                \
        _Pragma("unroll")                                                         \
        for (int nt = 0; nt < 4; ++nt) {                                          \
            short8 kf_ = *(const short8*)((KC) + SWZC(nt * 16 + l16, ks * 4 + quad)); \
            sf_[nt] = __builtin_amdgcn_mfma_f32_16x16x32_bf16(qf[ks], kf_, sf_[nt], 0, 0, 0); \
        }                                                                         \
    if ((T) == qt) {                                                              \
        _Pragma("unroll")                                                         \
        for (int nt = 0; nt < 4; ++nt)                                            \
            _Pragma("unroll")                                                     \
            for (int r = 0; r < 4; ++r)                                           \
                if (nt * 16 + l16 > qrow + r) sf_[nt][r] = -1e30f;                \
    }                                                                             \
    float alpha_[4], mS_[4];                                                      \
    _Pragma("unroll")                                                             \
    for (int r = 0; r < 4; ++r) {                                                 \
        float m_ = fmaxf(fmaxf(sf_[0][r], sf_[1][r]), fmaxf(sf_[2][r], sf_[3][r])); \
        _Pragma("unroll")                                                         \
        for (int off = 1; off < 16; off <<= 1)                                    \
            m_ = fmaxf(m_, __shfl_xor(m_, off));                                  \
        float nm_ = fmaxf(m_r[r], m_);                                            \
        alpha_[r] = __builtin_amdgcn_exp2f((m_r[r] - nm_) * SCL);                 \
        m_r[r] = nm_;                                                             \
        mS_[r] = nm_ * SCL;                                                       \
    }                                                                             \
    _Pragma("unroll")                                                             \
    for (int nt = 0; nt < 4; ++nt)                                                \
        _Pragma("unroll")                                                         \
        for (int r = 0; r < 4; ++r) {                                             \
            float p_ = __builtin_amdgcn_exp2f(fmaf(sf_[nt][r], SCL, -mS_[r]));    \
            int prow_ = quad * 4 + r;                                             \
            int chk_ = (nt * 2) | (l16 >> 3);                                     \
            Pw[prow_ * 64 + ((chk_ ^ (prow_ & 7)) << 3) + (l16 & 7)] = f2b(p_);   \
        }                                                                         \
    _Pragma("unroll")                                                             \
    for (int nt = 0; nt < 5; ++nt)                                                \
        _Pragma("unroll")                                                         \
        for (int r = 0; r < 4; ++r) ofr[nt][r] *= alpha_[r];                      \
    short8 pf_[2];                                                                \
    _Pragma("unroll")                                                             \
    for (int ks = 0; ks < 2; ++ks)                                                \
        pf_[ks] = *(const short8*)(Pw + l16 * 64 + (((ks * 4 + quad) ^ (l16 & 7)) << 3)); \
    __builtin_amdgcn_s_setprio(1);                                                \
    _Pragma("unroll")                                                             \
    for (int ks = 0; ks < 2; ++ks) {                                              \
        _Pragma("unroll")                                                         \
        for (int nt = 0; nt < 4; ++nt) {                                          \
            short8 vf_ = *(const short8*)((VC) + SWZC(nt * 16 + l16, ks * 4 + quad)); \
            ofr[nt] = __builtin_amdgcn_mfma_f32_16x16x32_bf16(pf_[ks], vf_, ofr[nt], 0, 0, 0); \
        }                                                                         \
        ofr[4] = __builtin_amdgcn_mfma_f32_16x16x32_bf16(pf_[ks], onesf, ofr[4], 0, 0, 0); \
    }                                                                             \
    __builtin_amdgcn_s_setprio(0);                                                \
    __syncthreads();                                                              \
} while (0)

    for (int kt = 0; kt <= qt; kt += 2) {
        FLASH_PHASE(Ks0, Vs0, Ks1, Vs1, kt);
        if (kt + 1 <= qt) FLASH_PHASE(Ks1, Vs1, Ks0, Vs0, kt + 1);
    }
#undef FLASH_PHASE

#pragma unroll
    for (int r = 0; r < 4; ++r) {
        float l = __shfl(ofr[4][r], (lane & 48));   // broadcast from l16==0 of this quad
        float rinv = 1.0f / l;
        float* op = attn_out + ((size_t)(b * LL) + q0 + qrow + r) * DD + h * 64 + l16;
#pragma unroll
        for (int nt = 0; nt < 4; ++nt)
            op[nt * 16] = ofr[nt][r] * rinv;
    }
    if (l16 == 0) {
#pragma unroll
        for (int r = 0; r < 4; ++r) {
            size_t si = (size_t)(q0 + qrow + r) * 2;
            stB[si]     = m_r[r];        // raw (QK+gb8) domain max
            stB[si + 1] = ofr[4][r];     // linear-domain sum
        }
    }
}

// ---------------- attn_w: distinct-array head double-buffer, inline kf reads ---------
// (round-2 version: best measured variant)
__global__ __launch_bounds__(256, 4) void attn_w_mfma(
        const ushort* __restrict__ Q16, const ushort* __restrict__ K16,
        const ushort* __restrict__ gb16, const float* __restrict__ stats,
        float* __restrict__ aw) {
    int qt = blockIdx.x >> 5, kt = blockIdx.x & 31;
    int b = blockIdx.y;
    int tid = threadIdx.x, wid = tid >> 6, lane = tid & 63;
    int quad = lane >> 4, l16 = lane & 15;
    int q0 = qt * 64, k0 = kt * 64;
    int qrow = wid * 16 + quad * 4;
    if (kt > qt) {
        int rr = tid >> 2, c0 = (tid & 3) * 16;
        float4 zv = make_float4(0.f, 0.f, 0.f, 0.f);
        float* p = aw + ((size_t)(b * LL) + q0 + rr) * LL + k0 + c0;
#pragma unroll
        for (int j = 0; j < 4; ++j) *(float4*)(p + j * 4) = zv;
        return;
    }
    __shared__ ushort Qs0[4096];
    __shared__ ushort Ks0[4096];
    __shared__ ushort Qs1[4096];
    __shared__ ushort Ks1[4096];
    float acc[4][4];
#pragma unroll
    for (int nt = 0; nt < 4; ++nt)
#pragma unroll
        for (int r = 0; r < 4; ++r) acc[nt][r] = 0.f;
    f32x4 gacc[4];
    const ushort* gbB = gb16 + (size_t)b * LL * LL;
#pragma unroll
    for (int r = 0; r < 4; ++r) {
        ushort4 g4 = *(const ushort4*)(gbB + (size_t)(q0 + qrow + r) * LL + k0 + l16 * 4);
        gacc[0][r] = b2f(g4.x);
        gacc[1][r] = b2f(g4.y);
        gacc[2][r] = b2f(g4.z);
        gacc[3][r] = b2f(g4.w);
    }
    bool diag = (kt == qt);
    stage_tile(Q16 + ((size_t)(b * 16) * LL + q0) * 64, 64, Qs0, tid);
    stage_tile(K16 + ((size_t)(b * 16) * LL + k0) * 64, 64, Ks0, tid);
    __syncthreads();

#define AW_PHASE(QC, KC, QN, KN, H) do {                                          \
    if ((H) < 15) {                                                               \
        stage_tile(Q16 + ((size_t)(b * 16 + (H) + 1) * LL + q0) * 64, 64, (QN), tid); \
        stage_tile(K16 + ((size_t)(b * 16 + (H) + 1) * LL + k0) * 64, 64, (KN), tid); \
    }                                                                             \
    short8 qf_[2];                                                                \
    _Pragma("unroll")                                                             \
    for (int ks = 0; ks < 2; ++ks)                                                \
        qf_[ks] = *(const short8*)((QC) + SWZC(wid * 16 + l16, ks * 4 + quad));   \
    float mS_[4], li_[4];                                                         \
    {                                                                             \
        const float* sp_ = stats + ((size_t)(b * 16 + (H)) * LL + q0 + qrow) * 2; \
        _Pragma("unroll")                                                         \
        for (int r = 0; r < 4; ++r) {                                             \
            mS_[r] = sp_[r * 2] * SCL;                                            \
            li_[r] = 1.0f / sp_[r * 2 + 1];                                       \
        }                                                                         \
    }                                                                             \
    f32x4 sf_[4];                                                                 \
    _Pragma("unroll")                                                             \
    for (int nt = 0; nt < 4; ++nt) sf_[nt] = gacc[nt];                            \
    __builtin_amdgcn_s_setprio(1);                                                \
    _Pragma("unroll")                                                             \
    for (int ks = 0; ks < 2; ++ks)                                                \
        _Pragma("unroll")                                                         \
        for (int nt = 0; nt < 4; ++nt) {                                          \
            short8 kf_ = *(const short8*)((KC) + SWZC(nt * 16 + l16, ks * 4 + quad)); \
            sf_[nt] = __builtin_amdgcn_mfma_f32_16x16x32_bf16(qf_[ks], kf_, sf_[nt], 0, 0, 0); \
        }                                                                         \
    __builtin_amdgcn_s_setprio(0);                                                \
    _Pragma("unroll")                                                             \
    for (int nt = 0; nt < 4; ++nt)                                                \
        _Pragma("unroll")                                                         \
        for (int r = 0; r < 4; ++r) {                                             \
            int row_ = qrow + r;                                                  \
            if (!diag || (nt * 16 + l16 <= row_))                                 \
                acc[nt][r] += __builtin_amdgcn_exp2f(fmaf(sf_[nt][r], SCL, -mS_[r])) * li_[r]; \
        }                                                                         \
    __syncthreads();                                                              \
} while (0)

    for (int h = 0; h < NHH; h += 2) {
        AW_PHASE(Qs0, Ks0, Qs1, Ks1, h);
        AW_PHASE(Qs1, Ks1, Qs0, Ks0, h + 1);
    }
#undef AW_PHASE

#pragma unroll
    for (int r = 0; r < 4; ++r) {
        float* op = aw + ((size_t)(b * LL) + q0 + qrow + r) * LL + k0 + l16;
#pragma unroll
        for (int nt = 0; nt < 4; ++nt)
            op[nt * 16] = acc[nt][r] * 0.0625f;
    }
}

// ---------------- adv = -nu*U*G, layernorm -> adv_n (bf16 out) ----------------
__global__ __launch_bounds__(256) void adv_ln_kernel(
        const float* __restrict__ U, const float* __restrict__ G,
        const float* __restrict__ nub, const float* __restrict__ lnw,
        const float* __restrict__ lnb, ushort* __restrict__ out) {
    int row = blockIdx.x, tid = threadIdx.x;
    size_t base = (size_t)row * DD + tid * 4;
    float4 u4 = *(const float4*)&U[base];
    float4 g4 = *(const float4*)&G[base];
    float nu = nub[row];
    float a[4];
    a[0] = -nu * u4.x * g4.x;
    a[1] = -nu * u4.y * g4.y;
    a[2] = -nu * u4.z * g4.z;
    a[3] = -nu * u4.w * g4.w;
    float ts = a[0] + a[1] + a[2] + a[3];
    float tq = a[0] * a[0] + a[1] * a[1] + a[2] * a[2] + a[3] * a[3];
    for (int off = 32; off; off >>= 1) {
        ts += __shfl_down(ts, off);
        tq += __shfl_down(tq, off);
    }
    __shared__ float r1[4], r2[4];
    if ((tid & 63) == 0) { r1[tid >> 6] = ts; r2[tid >> 6] = tq; }
    __syncthreads();
    __shared__ float s_mu, s_rs;
    if (tid == 0) {
        float S  = r1[0] + r1[1] + r1[2] + r1[3];
        float Qq = r2[0] + r2[1] + r2[2] + r2[3];
        float mu = S * (1.0f / 1024.f);
        float var = Qq * (1.0f / 1024.f) - mu * mu;
        s_mu = mu;
        s_rs = rsqrtf(var + 1e-5f);
    }
    __syncthreads();
    float mu = s_mu, rs = s_rs;
    float4 w4 = *(const float4*)&lnw[tid * 4];
    float4 b4 = *(const float4*)&lnb[tid * 4];
    ushort4 ov;
    ov.x = f2b((a[0] - mu) * rs * w4.x + b4.x);
    ov.y = f2b((a[1] - mu) * rs * w4.y + b4.y);
    ov.z = f2b((a[2] - mu) * rs * w4.z + b4.z);
    ov.w = f2b((a[3] - mu) * rs * w4.w + b4.w);
    *(ushort4*)&out[base] = ov;
}

// ---------------- final residual combine (sums split-K partials + Cb) ----------------
__global__ void final_kernel(const float* __restrict__ z, const float* __restrict__ ao,
                             const float* __restrict__ p0, const float* __restrict__ p1,
                             const float* __restrict__ Cb, float* __restrict__ out) {
    size_t i = ((size_t)blockIdx.x * 256 + threadIdx.x) * 4;
    int col = (int)(i & (DD - 1));
    float4 z4 = *(const float4*)&z[i];
    float4 a4 = *(const float4*)&ao[i];
    float4 m0 = *(const float4*)&p0[i];
    float4 m1 = *(const float4*)&p1[i];
    float4 cb = *(const float4*)&Cb[col];
    float4 o;
    o.x = z4.x + 0.42f * a4.x + 1.07f * (m0.x + m1.x + cb.x);
    o.y = z4.y + 0.42f * a4.y + 1.07f * (m0.y + m1.y + cb.y);
    o.z = z4.z + 0.42f * a4.z + 1.07f * (m0.z + m1.z + cb.z);
    o.w = z4.w + 0.42f * a4.w + 1.07f * (m0.w + m1.w + cb.w);
    *(float4*)&out[i] = o;
}

extern "C" void kernel_launch(void* const* d_in, const int* in_sizes, int n_in,
                              void* d_out, int out_size, void* d_ws, size_t ws_size,
                              hipStream_t stream) {
    const float* z       = (const float*)d_in[0];
    const float* Wq      = (const float*)d_in[1];
    const float* bq      = (const float*)d_in[2];
    const float* Wk      = (const float*)d_in[3];
    const float* bk      = (const float*)d_in[4];
    const float* Wv      = (const float*)d_in[5];
    const float* bv      = (const float*)d_in[6];
    const float* Wcoh    = (const float*)d_in[7];
    const float* gamma   = (const float*)d_in[8];
    const float* rg_w1   = (const float*)d_in[9];
    const float* rg_b1   = (const float*)d_in[10];
    const float* rg_w2   = (const float*)d_in[11];
    const float* rg_b2   = (const float*)d_in[12];
    const float* nu_diff = (const float*)d_in[13];
    const float* nu_adv  = (const float*)d_in[14];
    const float* nu_w1   = (const float*)d_in[15];
    const float* nu_b1   = (const float*)d_in[16];
    const float* nu_w2   = (const float*)d_in[17];
    const float* nu_b2   = (const float*)d_in[18];
    const float* Wu      = (const float*)d_in[19];
    const float* bu      = (const float*)d_in[20];
    const float* Wg      = (const float*)d_in[21];
    const float* bg      = (const float*)d_in[22];
    const float* ln_w    = (const float*)d_in[23];
    const float* ln_b    = (const float*)d_in[24];
    const float* Cw      = (const float*)d_in[25];
    const float* Cb      = (const float*)d_in[26];

    float* out_z  = (float*)d_out;
    float* out_aw = out_z + (size_t)MM * DD;

    float* ws = (float*)d_ws;
    const size_t MD = (size_t)MM * DD;   // 4,194,304
    float* pool  = ws;               // poolb (bf16, 8MB) then VT16 (bf16, reuses base)
    float* Qb    = ws + MD;          // later U, later mlp partial 0
    float* Kb    = ws + 2 * MD;      // later G, later mlp partial 1
    float* Vb    = ws + 3 * MD;      // later Q16/K16 (bf16)
    float* gkb   = ws + 4 * MD;      // scan partials; then gk16+K16r (bf16); then attn_out
    float* gbb   = ws + 5 * MD;      // Ab(8MB) + Wb(8MB, 4 slots) + gb16(16MB)
    float* H1    = ws + 7 * MD;      // MM*256
    float* N1    = H1 + (size_t)MM * HG;
    float* gate  = N1 + (size_t)MM * HN;
    float* nub   = gate + MM;
    float* stats = nub + MM;                       // B*NH*L*2
    float* ctot  = stats + (size_t)BB * NHH * LL * 2;  // B*NCH*DD

    char* gbase  = (char*)gbb;
    ushort* Ab   = (ushort*)gbase;                               // zb / z_glu / adv_n
    ushort* Wb   = (ushort*)(gbase + (size_t)8 * 1024 * 1024);   // 4 transposed weight slots
    ushort* gb16 = (ushort*)(gbase + (size_t)16 * 1024 * 1024);  // gb8 bf16 (pi layout)
    ushort* WtRG = Wb;                           // reuse slot 0 for rg after QKV
    ushort* WtNU = Wb + (size_t)1024 * 1024;     // slot 1 for nu
    ushort* Q16  = (ushort*)Vb;                  // [b,h,L,64]
    ushort* K16  = (ushort*)Vb + MD;             // [b,h,L,64]
    ushort* VT16 = (ushort*)pool;                // [b,h,64,L]
    ushort* poolb = (ushort*)pool;               // [b*L,1024] bf16 (dead before VT16)
    float*  part = gkb;                          // scan partials (fp32)
    ushort* gk16 = (ushort*)gkb;                 // [b*L,1024] bf16
    ushort* K16r = (ushort*)gkb + MD;            // [b*L,1024] bf16 (pre-RoPE K)

    // 1. pool scan (also emits z bf16 into Ab)
    pool_scan1<<<dim3(NCH, 4, BB), 256, 0, stream>>>(z, part, ctot, Ab);
    pool_scan2<<<dim3(NCH, 4, BB), 256, 0, stream>>>(part, ctot, poolb);
    // 2. weights QKV + Wcoh in one transpose-convert
    f2bT4_kernel<<<dim3(32, 32, 4), 256, 0, stream>>>(Wq, Wk, Wv, Wcoh, Wb);
    // 3. fused QKV + gk GEMM (1024 blocks = 4/CU, BK=64)
    gemm_mfma4<<<dim3(8, 32, 4), 256, 0, stream>>>(Ab, poolb, Wb, bq, bk, bv, Qb,
                                                   K16r, gk16);
    // 4. rg/nu weight transposes + gates GEMM (BK=64)
    f2bT_rgnu<<<dim3(8, 32, 2), 256, 0, stream>>>(rg_w1, nu_w1, WtRG, WtNU);
    gemm_gates<<<dim3(3, 32), 256, 0, stream>>>(poolb, WtRG, WtNU, rg_b1, nu_b1, H1, N1);
    // 5. gb8 (MFMA, bf16 out, pi column layout, BK=64)
    gb_mfma<<<dim3(256, BB), 256, 0, stream>>>(gk16, K16r, gamma, gb16);
    // 6. fused gate/nu finisher
    gatenu_fin<<<dim3(MM), 256, 0, stream>>>(H1, N1, rg_w2, rg_b2, nu_w2, nu_b2,
                                             nu_diff, nu_adv, gate, nub);
    // 7. V^T bf16 (poolb dead -> VT16 at pool base)
    vt16_kernel<<<dim3(32, 16, BB), 256, 0, stream>>>(Vb, VT16);
    // 8. rope Q,K -> bf16 head-blocked (into Vb region)
    rope_qk_bf16<<<dim3((MM * 512) / 256), 256, 0, stream>>>(Qb, Kb, gate, Q16, K16);
    // 9. MFMA flash attention (frozen r8: 1024 blocks, 4/CU, balanced qt mapping)
    attn_flash_mfma<<<dim3(NHH, 32, BB), 256, 0, stream>>>(Q16, K16, VT16, gb16, gkb, stats);
    // 10. attn_w -> second half of d_out
    attn_w_mfma<<<dim3(1024, BB), 256, 0, stream>>>(Q16, K16, gb16, stats, out_aw);
    // 11. z_glu bf16 directly into Ab
    rope_glu_b16<<<dim3((MM * 512) / 256), 256, 0, stream>>>(z, Ab);
    // 12. Wu/Wg/Cw transposes in one launch; fused U,G GEMM (512 blocks = 2/CU, BK=64)
    f2bT3_kernel<<<dim3(32, 32, 3), 256, 0, stream>>>(Wu, Wg, Cw, Wb);
    gemm_mfma4<<<dim3(8, 32, 2), 256, 0, stream>>>(Ab, Ab, Wb, bu, bg, bg, Qb,
                                                   nullptr, nullptr);
    // 13. adv + layernorm -> Ab (bf16, direct GEMM input)
    adv_ln_kernel<<<dim3(MM), 256, 0, stream>>>(Qb, Kb, nub, ln_w, ln_b, Ab);
    // 14. mlp partials = adv_n @ Cw (split-K=2, 512 blocks = 2/CU, BK=64) -> Qb, Kb
    gemm_splitk<<<dim3(8, 32, 2), 256, 0, stream>>>(Ab, Wb + (size_t)2 * 1024 * 1024,
                                                    Qb, Kb);
    // 15. final combine (adds partials + Cb)
    final_kernel<<<dim3(MD / 4 / 256), 256, 0, stream>>>(z, gkb, Qb, Kb, Cb, out_z);
}

// Round 11
// 547.864 us; speedup vs baseline: 1.0111x; 1.0111x over previous
//
#include <hip/hip_runtime.h>

#define DD 1024
#define NHH 16
#define HDD 64
#define BB 2
#define LL 2048
#define MM (BB*LL)          // 4096 rows
#define HG 256
#define HN 128

#define LOG_FAST 0.48121182f   // ln((1+sqrt(5))/2)
#define LOG_SLOW 7.3889461f    // ln(1618.0)
#define LOG_GLU  9.6915312f    // ln(16180.0)
#define SCL 0.18033688f        // 0.125 * log2(e); scores kept in (QK + 8*gb) raw domain

typedef __attribute__((ext_vector_type(8))) short short8;
typedef __attribute__((ext_vector_type(4))) float f32x4;

__device__ __forceinline__ float gelu_f(float x) {
    return 0.5f * x * (1.0f + erff(x * 0.70710678f));
}

__device__ __forceinline__ ushort f2b(float x) {
    unsigned u = __float_as_uint(x);
    unsigned r = (u + 0x7FFFu + ((u >> 16) & 1u)) >> 16;
    return (ushort)r;
}

__device__ __forceinline__ float b2f(ushort x) {
    return __uint_as_float(((unsigned)x) << 16);
}

__device__ __forceinline__ void gl_lds16(const ushort* g, ushort* l) {
    __builtin_amdgcn_global_load_lds(
        (const __attribute__((address_space(1))) unsigned int*)g,
        (__attribute__((address_space(3))) unsigned int*)l, 16, 0, 0);
}

// ushort offset of swizzled 16B chunk within a 64x64 bf16 tile
#define SWZC(row, c8) (((((row) << 3) | ((c8) ^ ((row) & 7)))) << 3)

// Stage a 64x64 bf16 tile (row-major, rstride in elements) into LDS with XOR swizzle.
__device__ __forceinline__ void stage_tile(const ushort* gsrc, int rstride,
                                           ushort* lds, int tid) {
    int wid = tid >> 6;
#pragma unroll
    for (int r = 0; r < 2; ++r) {
        int c = r * 256 + tid;
        int row = c >> 3;
        int c8 = (c & 7) ^ (row & 7);
        gl_lds16(gsrc + (size_t)row * rstride + c8 * 8,
                 lds + (size_t)(r * 256 + wid * 64) * 8);
    }
}

// ---------------- parallel causal cumulative mean pool (+ z->bf16 fused) ----------------
#define LCH 128
#define NCH 16
__global__ void pool_scan1(const float* __restrict__ z, float* __restrict__ part,
                           float* __restrict__ ctot, ushort* __restrict__ zb) {
    int ch = blockIdx.x, dg = blockIdx.y, b = blockIdx.z;
    int d = dg * 256 + threadIdx.x;
    size_t base = ((size_t)b * LL + ch * LCH) * DD + d;
    const float* zp = z + base;
    float* pp = part + base;
    ushort* zo = zb + base;
    float s = 0.f;
    for (int t = 0; t < LCH; ++t) {
        float v = zp[(size_t)t * DD];
        s += v;
        pp[(size_t)t * DD] = s;
        zo[(size_t)t * DD] = f2b(v);
    }
    ctot[((size_t)b * NCH + ch) * DD + d] = s;
}
__global__ void pool_scan2(const float* __restrict__ part, const float* __restrict__ ctot,
                           ushort* __restrict__ poolb) {
    int ch = blockIdx.x, dg = blockIdx.y, b = blockIdx.z;
    int d = dg * 256 + threadIdx.x;
    float off = 0.f;
    for (int c = 0; c < ch; ++c) off += ctot[((size_t)b * NCH + c) * DD + d];
    int t0 = ch * LCH;
    size_t base = ((size_t)b * LL + t0) * DD + d;
    const float* pp = part + base;
    ushort* po = poolb + base;
    for (int t = 0; t < LCH; ++t) {
        po[(size_t)t * DD] = f2b((pp[(size_t)t * DD] + off) / (float)(t0 + t + 1));
    }
}

// ---------------- unified weight transpose: all 9 weights in one launch --------------
// z 0..3: Wq,Wk,Wv,Wcoh -> Wb slots 0..3 (1024x1024 each)
// z 4..6: Wu,Wg,Cw      -> PU slots 0..2 (1024x1024 each)
// z 7:    rg_w1 (1024x256)  -> PU+3M      (256x1024)
// z 8:    nu_w1 (1024x128)  -> PU+3M+256K (128x1024)
__global__ void f2bT_all(const float* __restrict__ Wq, const float* __restrict__ Wk,
                         const float* __restrict__ Wv, const float* __restrict__ Wcoh,
                         const float* __restrict__ Wu, const float* __restrict__ Wg,
                         const float* __restrict__ Cw, const float* __restrict__ Wrg,
                         const float* __restrict__ Wnu, ushort* __restrict__ Wb,
                         ushort* __restrict__ PU) {
    int zc = blockIdx.z;
    const float* W;
    ushort* dst;
    int Ndim = 1024;
    switch (zc) {
        case 0: W = Wq;   dst = Wb; break;
        case 1: W = Wk;   dst = Wb + (size_t)1 * 1024 * 1024; break;
        case 2: W = Wv;   dst = Wb + (size_t)2 * 1024 * 1024; break;
        case 3: W = Wcoh; dst = Wb + (size_t)3 * 1024 * 1024; break;
        case 4: W = Wu;   dst = PU; break;
        case 5: W = Wg;   dst = PU + (size_t)1 * 1024 * 1024; break;
        case 6: W = Cw;   dst = PU + (size_t)2 * 1024 * 1024; break;
        case 7: W = Wrg;  dst = PU + (size_t)3 * 1024 * 1024; Ndim = HG;
                if (blockIdx.x >= 8) return; break;
        default: W = Wnu; dst = PU + (size_t)3 * 1024 * 1024 + 256 * 1024; Ndim = HN;
                if (blockIdx.x >= 4) return; break;
    }
    __shared__ float t[32][33];
    int n0 = blockIdx.x * 32, k0 = blockIdx.y * 32;
    int tx = threadIdx.x & 31, ty = threadIdx.x >> 5;
#pragma unroll
    for (int j = 0; j < 4; ++j)
        t[ty + j * 8][tx] = W[(size_t)(k0 + ty + j * 8) * Ndim + n0 + tx];
    __syncthreads();
#pragma unroll
    for (int j = 0; j < 4; ++j)
        dst[(size_t)(n0 + ty + j * 8) * 1024 + k0 + tx] = f2b(t[tx][ty + j * 8]);
}

// ---------------- fused 4-slice GEMM (BK=32, measured-best r9 body) ------------------
// zid 0..2: C = Az @ Wt[zid]^T + bias[zid] (fp32), zid==1 also emits bf16 K16r.
// zid 3:    gk16 = f2b(Ap @ Wt[3]^T)  (bf16, no bias).
__global__ __launch_bounds__(256) void gemm_mfma4(
        const ushort* __restrict__ Az, const ushort* __restrict__ Ap,
        const ushort* __restrict__ Wt,
        const float* __restrict__ b0, const float* __restrict__ b1,
        const float* __restrict__ b2, float* __restrict__ C,
        ushort* __restrict__ K16r, ushort* __restrict__ gk16) {
    int zid = blockIdx.z;
    const ushort* A = (zid < 3) ? Az : Ap;
    const ushort* W = Wt + (size_t)zid * 1024 * 1024;
    __shared__ ushort As[4096];
    __shared__ ushort Bs[4096];
    int tid = threadIdx.x;
    int wid = tid >> 6, lane = tid & 63;
    int n0 = blockIdx.x * 128, m0 = blockIdx.y * 128;
    int wm = wid >> 1, wn = wid & 1;
    int quad = lane >> 4, l16 = lane & 15;

    f32x4 acc[4][4];
#pragma unroll
    for (int mi = 0; mi < 4; ++mi)
#pragma unroll
        for (int ni = 0; ni < 4; ++ni) acc[mi][ni] = (f32x4){0.f, 0.f, 0.f, 0.f};

    int c0 = wid * 128 + lane;
    int c1 = c0 + 64;
    const ushort* Ag0 = A + (size_t)(m0 + (c0 & 127)) * 1024 + (c0 >> 7) * 8;
    const ushort* Ag1 = A + (size_t)(m0 + (c1 & 127)) * 1024 + (c1 >> 7) * 8;
    const ushort* Bg0 = W + (size_t)(n0 + (c0 & 127)) * 1024 + (c0 >> 7) * 8;
    const ushort* Bg1 = W + (size_t)(n0 + (c1 & 127)) * 1024 + (c1 >> 7) * 8;
    ushort* Al0 = As + wid * 1024;
    ushort* Al1 = As + wid * 1024 + 512;
    ushort* Bl0 = Bs + wid * 1024;
    ushort* Bl1 = Bs + wid * 1024 + 512;

    const ushort* a_rd = &As[(quad * 128 + wm * 64 + l16) * 8];
    const ushort* b_rd = &Bs[(quad * 128 + wn * 64 + l16) * 8];

    for (int kb = 0; kb < 1024; kb += 32) {
        gl_lds16(Ag0 + kb, Al0);
        gl_lds16(Ag1 + kb, Al1);
        gl_lds16(Bg0 + kb, Bl0);
        gl_lds16(Bg1 + kb, Bl1);
        __syncthreads();
        short8 af[4], bf[4];
#pragma unroll
        for (int mi = 0; mi < 4; ++mi)
            af[mi] = *(const short8*)(a_rd + mi * 16 * 8);
#pragma unroll
        for (int ni = 0; ni < 4; ++ni)
            bf[ni] = *(const short8*)(b_rd + ni * 16 * 8);
#pragma unroll
        for (int mi = 0; mi < 4; ++mi)
#pragma unroll
            for (int ni = 0; ni < 4; ++ni)
                acc[mi][ni] = __builtin_amdgcn_mfma_f32_16x16x32_bf16(
                    af[mi], bf[ni], acc[mi][ni], 0, 0, 0);
        __syncthreads();
    }
    int bcol[4];
#pragma unroll
    for (int ni = 0; ni < 4; ++ni) bcol[ni] = n0 + wn * 64 + ni * 16 + l16;

    if (zid == 3) {
#pragma unroll
        for (int mi = 0; mi < 4; ++mi) {
#pragma unroll
            for (int r = 0; r < 4; ++r) {
                int row = m0 + wm * 64 + mi * 16 + quad * 4 + r;
                ushort* Cp = gk16 + (size_t)row * 1024;
#pragma unroll
                for (int ni = 0; ni < 4; ++ni)
                    Cp[bcol[ni]] = f2b(acc[mi][ni][r]);
            }
        }
        return;
    }
    const float* bias = zid == 0 ? b0 : (zid == 1 ? b1 : b2);
    float* Cz = C + (size_t)zid * (size_t)MM * DD;
    float bval[4];
#pragma unroll
    for (int ni = 0; ni < 4; ++ni) bval[ni] = bias[bcol[ni]];
    bool doK = (zid == 1) && (K16r != nullptr);
#pragma unroll
    for (int mi = 0; mi < 4; ++mi) {
#pragma unroll
        for (int r = 0; r < 4; ++r) {
            int row = m0 + wm * 64 + mi * 16 + quad * 4 + r;
            float* Cp = Cz + (size_t)row * 1024;
            ushort* Kp = K16r + (size_t)row * 1024;
#pragma unroll
            for (int ni = 0; ni < 4; ++ni) {
                float v = acc[mi][ni][r] + bval[ni];
                Cp[bcol[ni]] = v;
                if (doK) Kp[bcol[ni]] = f2b(v);
            }
        }
    }
}

// ---------------- split-K GEMM for mlp_out (BK=32): two K-halves to partials ---------
__global__ __launch_bounds__(256) void gemm_splitk(
        const ushort* __restrict__ A, const ushort* __restrict__ Wt,
        float* __restrict__ C0, float* __restrict__ C1) {
    int zid = blockIdx.z;
    float* C = zid ? C1 : C0;
    int kbase = zid * 512;
    __shared__ ushort As[4096];
    __shared__ ushort Bs[4096];
    int tid = threadIdx.x;
    int wid = tid >> 6, lane = tid & 63;
    int n0 = blockIdx.x * 128, m0 = blockIdx.y * 128;
    int wm = wid >> 1, wn = wid & 1;
    int quad = lane >> 4, l16 = lane & 15;

    f32x4 acc[4][4];
#pragma unroll
    for (int mi = 0; mi < 4; ++mi)
#pragma unroll
        for (int ni = 0; ni < 4; ++ni) acc[mi][ni] = (f32x4){0.f, 0.f, 0.f, 0.f};

    int c0 = wid * 128 + lane;
    int c1 = c0 + 64;
    const ushort* Ag0 = A + (size_t)(m0 + (c0 & 127)) * 1024 + (c0 >> 7) * 8 + kbase;
    const ushort* Ag1 = A + (size_t)(m0 + (c1 & 127)) * 1024 + (c1 >> 7) * 8 + kbase;
    const ushort* Bg0 = Wt + (size_t)(n0 + (c0 & 127)) * 1024 + (c0 >> 7) * 8 + kbase;
    const ushort* Bg1 = Wt + (size_t)(n0 + (c1 & 127)) * 1024 + (c1 >> 7) * 8 + kbase;
    ushort* Al0 = As + wid * 1024;
    ushort* Al1 = As + wid * 1024 + 512;
    ushort* Bl0 = Bs + wid * 1024;
    ushort* Bl1 = Bs + wid * 1024 + 512;

    const ushort* a_rd = &As[(quad * 128 + wm * 64 + l16) * 8];
    const ushort* b_rd = &Bs[(quad * 128 + wn * 64 + l16) * 8];

    for (int kb = 0; kb < 512; kb += 32) {
        gl_lds16(Ag0 + kb, Al0);
        gl_lds16(Ag1 + kb, Al1);
        gl_lds16(Bg0 + kb, Bl0);
        gl_lds16(Bg1 + kb, Bl1);
        __syncthreads();
        short8 af[4], bf[4];
#pragma unroll
        for (int mi = 0; mi < 4; ++mi)
            af[mi] = *(const short8*)(a_rd + mi * 16 * 8);
#pragma unroll
        for (int ni = 0; ni < 4; ++ni)
            bf[ni] = *(const short8*)(b_rd + ni * 16 * 8);
#pragma unroll
        for (int mi = 0; mi < 4; ++mi)
#pragma unroll
            for (int ni = 0; ni < 4; ++ni)
                acc[mi][ni] = __builtin_amdgcn_mfma_f32_16x16x32_bf16(
                    af[mi], bf[ni], acc[mi][ni], 0, 0, 0);
        __syncthreads();
    }
#pragma unroll
    for (int mi = 0; mi < 4; ++mi) {
#pragma unroll
        for (int r = 0; r < 4; ++r) {
            int row = m0 + wm * 64 + mi * 16 + quad * 4 + r;
            float* Cp = C + (size_t)row * 1024;
#pragma unroll
            for (int ni = 0; ni < 4; ++ni)
                Cp[n0 + wn * 64 + ni * 16 + l16] = acc[mi][ni][r];
        }
    }
}

// ---------------- fused H1/N1 GEMM (BK=32): x<2 -> H1 (256), else N1 (128) -----------
__global__ __launch_bounds__(256) void gemm_gates(
        const ushort* __restrict__ A, const ushort* __restrict__ WtRG,
        const ushort* __restrict__ WtNU, const float* __restrict__ rg_b1,
        const float* __restrict__ nu_b1, float* __restrict__ H1,
        float* __restrict__ N1) {
    int bx = blockIdx.x;
    bool isH = bx < 2;
    const ushort* Wt = isH ? WtRG : WtNU;
    const float* bias = isH ? rg_b1 : nu_b1;
    float* C = isH ? H1 : N1;
    int Ndim = isH ? HG : HN;
    int n0 = isH ? bx * 128 : 0;
    int m0 = blockIdx.y * 128;
    __shared__ ushort As[4096];
    __shared__ ushort Bs[4096];
    int tid = threadIdx.x;
    int wid = tid >> 6, lane = tid & 63;
    int wm = wid >> 1, wn = wid & 1;
    int quad = lane >> 4, l16 = lane & 15;

    f32x4 acc[4][4];
#pragma unroll
    for (int mi = 0; mi < 4; ++mi)
#pragma unroll
        for (int ni = 0; ni < 4; ++ni) acc[mi][ni] = (f32x4){0.f, 0.f, 0.f, 0.f};

    int c0 = wid * 128 + lane;
    int c1 = c0 + 64;
    const ushort* Ag0 = A + (size_t)(m0 + (c0 & 127)) * 1024 + (c0 >> 7) * 8;
    const ushort* Ag1 = A + (size_t)(m0 + (c1 & 127)) * 1024 + (c1 >> 7) * 8;
    const ushort* Bg0 = Wt + (size_t)(n0 + (c0 & 127)) * 1024 + (c0 >> 7) * 8;
    const ushort* Bg1 = Wt + (size_t)(n0 + (c1 & 127)) * 1024 + (c1 >> 7) * 8;
    ushort* Al0 = As + wid * 1024;
    ushort* Al1 = As + wid * 1024 + 512;
    ushort* Bl0 = Bs + wid * 1024;
    ushort* Bl1 = Bs + wid * 1024 + 512;

    const ushort* a_rd = &As[(quad * 128 + wm * 64 + l16) * 8];
    const ushort* b_rd = &Bs[(quad * 128 + wn * 64 + l16) * 8];

    for (int kb = 0; kb < 1024; kb += 32) {
        gl_lds16(Ag0 + kb, Al0);
        gl_lds16(Ag1 + kb, Al1);
        gl_lds16(Bg0 + kb, Bl0);
        gl_lds16(Bg1 + kb, Bl1);
        __syncthreads();
        short8 af[4], bf[4];
#pragma unroll
        for (int mi = 0; mi < 4; ++mi)
            af[mi] = *(const short8*)(a_rd + mi * 16 * 8);
#pragma unroll
        for (int ni = 0; ni < 4; ++ni)
            bf[ni] = *(const short8*)(b_rd + ni * 16 * 8);
#pragma unroll
        for (int mi = 0; mi < 4; ++mi)
#pragma unroll
            for (int ni = 0; ni < 4; ++ni)
                acc[mi][ni] = __builtin_amdgcn_mfma_f32_16x16x32_bf16(
                    af[mi], bf[ni], acc[mi][ni], 0, 0, 0);
        __syncthreads();
    }
    int bcol[4];
    float bval[4];
#pragma unroll
    for (int ni = 0; ni < 4; ++ni) {
        bcol[ni] = n0 + wn * 64 + ni * 16 + l16;
        bval[ni] = bias[bcol[ni]];
    }
#pragma unroll
    for (int mi = 0; mi < 4; ++mi) {
#pragma unroll
        for (int r = 0; r < 4; ++r) {
            int row = m0 + wm * 64 + mi * 16 + quad * 4 + r;
            float* Cp = C + (size_t)row * Ndim;
#pragma unroll
            for (int ni = 0; ni < 4; ++ni)
                Cp[bcol[ni]] = acc[mi][ni][r] + bval[ni];
        }
    }
}

// ---------------- gb8 (bf16, BK=32) = 8*tanh(gamma)/32 * gk16 @ K16r^T ---------------
// pi-permuted output: value for k-local (nt*16+l16) stored at position l16*4+nt.
__global__ __launch_bounds__(256) void gb_mfma(
        const ushort* __restrict__ gk16, const ushort* __restrict__ K16r,
        const float* __restrict__ gamma, ushort* __restrict__ gb) {
    int lt = blockIdx.x >> 4, mt = blockIdx.x & 15;
    if (mt > lt) return;
    int b = blockIdx.y;
    __shared__ ushort As[4096];
    __shared__ ushort Bs[4096];
    int tid = threadIdx.x;
    int wid = tid >> 6, lane = tid & 63;
    int l0 = lt * 128, m0 = mt * 128;
    int wm = wid >> 1, wn = wid & 1;
    int quad = lane >> 4, l16 = lane & 15;

    f32x4 acc[4][4];
#pragma unroll
    for (int mi = 0; mi < 4; ++mi)
#pragma unroll
        for (int ni = 0; ni < 4; ++ni) acc[mi][ni] = (f32x4){0.f, 0.f, 0.f, 0.f};

    int c0 = wid * 128 + lane;
    int c1 = c0 + 64;
    const ushort* Ag0 = gk16 + ((size_t)b * LL + l0 + (c0 & 127)) * 1024 + (c0 >> 7) * 8;
    const ushort* Ag1 = gk16 + ((size_t)b * LL + l0 + (c1 & 127)) * 1024 + (c1 >> 7) * 8;
    const ushort* Bg0 = K16r + ((size_t)b * LL + m0 + (c0 & 127)) * 1024 + (c0 >> 7) * 8;
    const ushort* Bg1 = K16r + ((size_t)b * LL + m0 + (c1 & 127)) * 1024 + (c1 >> 7) * 8;
    ushort* Al0 = As + wid * 1024;
    ushort* Al1 = As + wid * 1024 + 512;
    ushort* Bl0 = Bs + wid * 1024;
    ushort* Bl1 = Bs + wid * 1024 + 512;

    const ushort* a_rd = &As[(quad * 128 + wm * 64 + l16) * 8];
    const ushort* b_rd = &Bs[(quad * 128 + wn * 64 + l16) * 8];

    for (int kb = 0; kb < 1024; kb += 32) {
        gl_lds16(Ag0 + kb, Al0);
        gl_lds16(Ag1 + kb, Al1);
        gl_lds16(Bg0 + kb, Bl0);
        gl_lds16(Bg1 + kb, Bl1);
        __syncthreads();
        short8 af[4], bf[4];
#pragma unroll
        for (int mi = 0; mi < 4; ++mi)
            af[mi] = *(const short8*)(a_rd + mi * 16 * 8);
#pragma unroll
        for (int ni = 0; ni < 4; ++ni)
            bf[ni] = *(const short8*)(b_rd + ni * 16 * 8);
#pragma unroll
        for (int mi = 0; mi < 4; ++mi)
#pragma unroll
            for (int ni = 0; ni < 4; ++ni)
                acc[mi][ni] = __builtin_amdgcn_mfma_f32_16x16x32_bf16(
                    af[mi], bf[ni], acc[mi][ni], 0, 0, 0);
        __syncthreads();
    }
    float scale = tanhf(gamma[0]) * 0.25f;   // (1/32) * 8
#pragma unroll
    for (int mi = 0; mi < 4; ++mi) {
#pragma unroll
        for (int r = 0; r < 4; ++r) {
            int row = l0 + wm * 64 + mi * 16 + quad * 4 + r;
            ushort* Cp = gb + ((size_t)b * LL + row) * LL;
            ushort4 o;
            o.x = f2b(acc[mi][0][r] * scale);
            o.y = f2b(acc[mi][1][r] * scale);
            o.z = f2b(acc[mi][2][r] * scale);
            o.w = f2b(acc[mi][3][r] * scale);
            *(ushort4*)(Cp + m0 + wn * 64 + l16 * 4) = o;
        }
    }
}

// ---------------- fused gate + nu finisher ----------------
__global__ __launch_bounds__(256) void gatenu_fin(
        const float* __restrict__ H1, const float* __restrict__ N1,
        const float* __restrict__ rg_w2, const float* __restrict__ rg_b2,
        const float* __restrict__ nu_w2, const float* __restrict__ nu_b2,
        const float* __restrict__ nu_diff, const float* __restrict__ nu_adv,
        float* __restrict__ gate, float* __restrict__ nub) {
    int row = blockIdx.x, tid = threadIdx.x;
    float gv = gelu_f(H1[(size_t)row * HG + tid]) * rg_w2[tid];
    float nv = (tid < HN) ? tanhf(N1[(size_t)row * HN + tid]) * nu_w2[tid] : 0.f;
    for (int off = 32; off; off >>= 1) {
        gv += __shfl_down(gv, off);
        nv += __shfl_down(nv, off);
    }
    __shared__ float pg[4], pn[4];
    if ((tid & 63) == 0) { pg[tid >> 6] = gv; pn[tid >> 6] = nv; }
    __syncthreads();
    if (tid == 0) {
        float ga = pg[0] + pg[1] + pg[2] + pg[3] + rg_b2[0];
        gate[row] = 1.f / (1.f + expf(-ga));
        float na = pn[0] + pn[1] + pn[2] + pn[3] + nu_b2[0];
        nub[row] = fabsf(nu_diff[0]) + tanhf(na) * fabsf(nu_adv[0]);
    }
}

// ---------------- gated dual-base RoPE on Q and K -> bf16 head-blocked [b,h,L,64] -------
__global__ void rope_qk_bf16(const float* __restrict__ Q, const float* __restrict__ K,
                             const float* __restrict__ gate,
                             ushort* __restrict__ Q16, ushort* __restrict__ K16) {
    int idx = blockIdx.x * 256 + threadIdx.x;   // over MM*512
    int row = idx >> 9;
    int i = idx & 511;
    int b = row >> 11, t = row & (LL - 1);
    float g = gate[row];
    float fi = (float)i * (1.0f / 512.0f);
    float tf = (float)t;
    float af = tf * expf(-fi * LOG_FAST);
    float as = tf * expf(-fi * LOG_SLOW);
    float c = g * cosf(af) + (1.f - g) * cosf(as);
    float s = g * sinf(af) + (1.f - g) * sinf(as);
    size_t base = (size_t)row * DD;
    float x = Q[base + i], y = Q[base + 512 + i];
    float q1 = x * c - y * s, q2 = y * c + x * s;
    x = K[base + i]; y = K[base + 512 + i];
    float k1 = x * c - y * s, k2 = y * c + x * s;
    int h1 = i >> 6, d1 = i & 63;
    size_t o1 = ((size_t)(b * 16 + h1) * LL + t) * 64 + d1;
    size_t o2 = ((size_t)(b * 16 + 8 + h1) * LL + t) * 64 + d1;
    Q16[o1] = f2b(q1); Q16[o2] = f2b(q2);
    K16[o1] = f2b(k1); K16[o2] = f2b(k2);
}

// ---------------- V fp32 [b*L,1024] -> V^T bf16 [b,h,64,L] ----------------
__global__ __launch_bounds__(256) void vt16_kernel(const float* __restrict__ V,
                                                   ushort* __restrict__ VT) {
    __shared__ ushort t[64][72];
    int lb = blockIdx.x, hb = blockIdx.y, b = blockIdx.z;
    int tid = threadIdx.x;
    {
        int l = tid >> 2, c0 = (tid & 3) * 16;
        const float* Vp = V + ((size_t)(b * LL) + lb * 64 + l) * DD + hb * 64 + c0;
#pragma unroll
        for (int j = 0; j < 4; ++j) {
            float4 v = *(const float4*)(Vp + j * 4);
            t[l][c0 + j * 4 + 0] = f2b(v.x);
            t[l][c0 + j * 4 + 1] = f2b(v.y);
            t[l][c0 + j * 4 + 2] = f2b(v.z);
            t[l][c0 + j * 4 + 3] = f2b(v.w);
        }
    }
    __syncthreads();
    {
        int d = tid >> 2, l0 = (tid & 3) * 16;
        ushort tmp[16];
#pragma unroll
        for (int j = 0; j < 16; ++j) tmp[j] = t[l0 + j][d];
        ushort* Op = VT + ((size_t)((b * 16 + hb) * 64) + d) * LL + lb * 64 + l0;
        *(ushort4*)(Op + 0)  = *(ushort4*)&tmp[0];
        *(ushort4*)(Op + 4)  = *(ushort4*)&tmp[4];
        *(ushort4*)(Op + 8)  = *(ushort4*)&tmp[8];
        *(ushort4*)(Op + 12) = *(ushort4*)&tmp[12];
    }
}

// ---------------- fixed-base RoPE for GLU branch, bf16 output ----------------
__global__ void rope_glu_b16(const float* __restrict__ z, ushort* __restrict__ zg) {
    int idx = blockIdx.x * 256 + threadIdx.x;
    int row = idx >> 9;
    int i = idx & 511;
    int t = row & (LL - 1);
    float fi = (float)i * (1.0f / 512.0f);
    float ag = (float)t * expf(-fi * LOG_GLU);
    float c = cosf(ag), s = sinf(ag);
    size_t base = (size_t)row * DD;
    float x = z[base + i], y = z[base + 512 + i];
    zg[base + i]       = f2b(x * c - y * s);
    zg[base + 512 + i] = f2b(y * c + x * s);
}

// ---------------- MFMA flash attention (FROZEN, round-8 measured 68.5us) -------------
__global__ __launch_bounds__(256, 4) void attn_flash_mfma(
        const ushort* __restrict__ Q16, const ushort* __restrict__ K16,
        const ushort* __restrict__ VT16, const ushort* __restrict__ gb16,
        float* __restrict__ attn_out, float* __restrict__ stats) {
    int h = blockIdx.x;
    int yy = blockIdx.y;
    int b = blockIdx.z;
    int qt = (yy < 16) ? yy : (47 - yy);
    int q0 = qt * 64;
    __shared__ ushort Ks0[4096];
    __shared__ ushort Vs0[4096];
    __shared__ ushort Ks1[4096];
    __shared__ ushort Vs1[4096];
    __shared__ ushort Ps[4096];        // per-wave 16x64 swizzled P (wid*1024)
    int tid = threadIdx.x, wid = tid >> 6, lane = tid & 63;
    int quad = lane >> 4, l16 = lane & 15;
    const ushort* Qg = Q16 + ((size_t)(b * 16 + h) * LL) * 64;
    const ushort* Kg = K16 + ((size_t)(b * 16 + h) * LL) * 64;
    const ushort* Vg = VT16 + ((size_t)(b * 16 + h) * 64) * LL;
    const ushort* gbB = gb16 + (size_t)b * LL * LL;
    float* stB = stats + ((size_t)(b * 16 + h) * LL) * 2;
    int qrow = wid * 16 + quad * 4;
    ushort* Pw = Ps + wid * 1024;

    short ov = (l16 == 0) ? (short)0x3F80 : (short)0;
    short8 onesf = {ov, ov, ov, ov, ov, ov, ov, ov};

    short8 qf[2];
    {
        const ushort* qp = Qg + (size_t)(q0 + wid * 16 + l16) * 64 + quad * 8;
        qf[0] = *(const short8*)(qp);
        qf[1] = *(const short8*)(qp + 32);
    }
    stage_tile(Kg, 64, Ks0, tid);
    stage_tile(Vg, LL, Vs0, tid);
    __syncthreads();

    f32x4 ofr[5];   // [0..3]=O cols, [4]=row-sum l (lives in l16==0 lanes)
    float m_r[4];
#pragma unroll
    for (int nt = 0; nt < 5; ++nt) ofr[nt] = (f32x4){0.f, 0.f, 0.f, 0.f};
#pragma unroll
    for (int r = 0; r < 4; ++r) m_r[r] = -3e38f;

#define FLASH_PHASE(KC, VC, KN, VN, T) do {                                       \
    int k0_ = (T) * 64;                                                           \
    if ((T) + 1 <= qt) {                                                          \
        stage_tile(Kg + (size_t)(k0_ + 64) * 64, 64, (KN), tid);                  \
        stage_tile(Vg + (k0_ + 64), LL, (VN), tid);                               \
    }                                                                             \
    f32x4 sf_[4];                                                                 \
    _Pragma("unroll")                                                             \
    for (int r = 0; r < 4; ++r) {                                                 \
        ushort4 g4_ = *(const ushort4*)(gbB + (size_t)(q0 + qrow + r) * LL + k0_ + l16 * 4); \
        sf_[0][r] = b2f(g4_.x); sf_[1][r] = b2f(g4_.y);                           \
        sf_[2][r] = b2f(g4_.z); sf_[3][r] = b2f(g4_.w);                           \
    }                                                                             \
    _Pragma("unroll")                                                             \
    for (int ks = 0; ks < 2; ++ks)                                                \
        _Pragma("unroll")                                                         \
        for (int nt = 0; nt < 4; ++nt) {                                          \
            short8 kf_ = *(const short8*)((KC) + SWZC(nt * 16 + l16, ks * 4 + quad)); \
            sf_[nt] = __builtin_amdgcn_mfma_f32_16x16x32_bf16(qf[ks], kf_, sf_[nt], 0, 0, 0); \
        }                                                                         \
    if ((T) == qt) {                                                              \
        _Pragma("unroll")                                                         \
        for (int nt = 0; nt < 4; ++nt)                                            \
            _Pragma("unroll")                                                     \
            for (int r = 0; r < 4; ++r)                                           \
                if (nt * 16 + l16 > qrow + r) sf_[nt][r] = -1e30f;                \
    }                                                                             \
    float alpha_[4], mS_[4];                                                      \
    _Pragma("unroll")                                                             \
    for (int r = 0; r < 4; ++r) {                                                 \
        float m_ = fmaxf(fmaxf(sf_[0][r], sf_[1][r]), fmaxf(sf_[2][r], sf_[3][r])); \
        _Pragma("unroll")                                                         \
        for (int off = 1; off < 16; off <<= 1)                                    \
            m_ = fmaxf(m_, __shfl_xor(m_, off));                                  \
        float nm_ = fmaxf(m_r[r], m_);                                            \
        alpha_[r] = __builtin_amdgcn_exp2f((m_r[r] - nm_) * SCL);                 \
        m_r[r] = nm_;                                                             \
        mS_[r] = nm_ * SCL;                                                       \
    }                                                                             \
    _Pragma("unroll")                                                             \
    for (int nt = 0; nt < 4; ++nt)                                                \
        _Pragma("unroll")                                                         \
        for (int r = 0; r < 4; ++r) {                                             \
            float p_ = __builtin_amdgcn_exp2f(fmaf(sf_[nt][r], SCL, -mS_[r]));    \
            int prow_ = quad * 4 + r;                                             \
            int chk_ = (nt * 2) | (l16 >> 3);                                     \
            Pw[prow_ * 64 + ((chk_ ^ (prow_ & 7)) << 3) + (l16 & 7)] = f2b(p_);   \
        }                                                                         \
    _Pragma("unroll")                                                             \
    for (int nt = 0; nt < 5; ++nt)                                                \
        _Pragma("unroll")                                                         \
        for (int r = 0; r < 4; ++r) ofr[nt][r] *= alpha_[r];                      \
    short8 pf_[2];                                                                \
    _Pragma("unroll")                                                             \
    for (int ks = 0; ks < 2; ++ks)                                                \
        pf_[ks] = *(const short8*)(Pw + l16 * 64 + (((ks * 4 + quad) ^ (l16 & 7)) << 3)); \
    __builtin_amdgcn_s_setprio(1);                                                \
    _Pragma("unroll")                                                             \
    for (int ks = 0; ks < 2; ++ks) {                                              \
        _Pragma("unroll")                                                         \
        for (int nt = 0; nt < 4; ++nt) {                                          \
            short8 vf_ = *(const short8*)((VC) + SWZC(nt * 16 + l16, ks * 4 + quad)); \
            ofr[nt] = __builtin_amdgcn_mfma_f32_16x16x32_bf16(pf_[ks], vf_, ofr[nt], 0, 0, 0); \
        }                                                                         \
        ofr[4] = __builtin_amdgcn_mfma_f32_16x16x32_bf16(pf_[ks], onesf, ofr[4], 0, 0, 0); \
    }                                                                             \
    __builtin_amdgcn_s_setprio(0);                                                \
    __syncthreads();                                                              \
} while (0)

    for (int kt = 0; kt <= qt; kt += 2) {
        FLASH_PHASE(Ks0, Vs0, Ks1, Vs1, kt);
        if (kt + 1 <= qt) FLASH_PHASE(Ks1, Vs1, Ks0, Vs0, kt + 1);
    }
#undef FLASH_PHASE

#pragma unroll
    for (int r = 0; r < 4; ++r) {
        float l = __shfl(ofr[4][r], (lane & 48));   // broadcast from l16==0 of this quad
        float rinv = 1.0f / l;
        float* op = attn_out + ((size_t)(b * LL) + q0 + qrow + r) * DD + h * 64 + l16;
#pragma unroll
        for (int nt = 0; nt < 4; ++nt)
            op[nt * 16] = ofr[nt][r] * rinv;
    }
    if (l16 == 0) {
#pragma unroll
        for (int r = 0; r < 4; ++r) {
            size_t si = (size_t)(q0 + qrow + r) * 2;
            stB[si]     = m_r[r];        // raw (QK+gb8) domain max
            stB[si + 1] = ofr[4][r];     // linear-domain sum
        }
    }
}

// ---------------- attn_w: distinct-array head double-buffer, inline kf reads ---------
__global__ __launch_bounds__(256, 4) void attn_w_mfma(
        const ushort* __restrict__ Q16, const ushort* __restrict__ K16,
        const ushort* __restrict__ gb16, const float* __restrict__ stats,
        float* __restrict__ aw) {
    int qt = blockIdx.x >> 5, kt = blockIdx.x & 31;
    int b = blockIdx.y;
    int tid = threadIdx.x, wid = tid >> 6, lane = tid & 63;
    int quad = lane >> 4, l16 = lane & 15;
    int q0 = qt * 64, k0 = kt * 64;
    int qrow = wid * 16 + quad * 4;
    if (kt > qt) {
        int rr = tid >> 2, c0 = (tid & 3) * 16;
        float4 zv = make_float4(0.f, 0.f, 0.f, 0.f);
        float* p = aw + ((size_t)(b * LL) + q0 + rr) * LL + k0 + c0;
#pragma unroll
        for (int j = 0; j < 4; ++j) *(float4*)(p + j * 4) = zv;
        return;
    }
    __shared__ ushort Qs0[4096];
    __shared__ ushort Ks0[4096];
    __shared__ ushort Qs1[4096];
    __shared__ ushort Ks1[4096];
    float acc[4][4];
#pragma unroll
    for (int nt = 0; nt < 4; ++nt)
#pragma unroll
        for (int r = 0; r < 4; ++r) acc[nt][r] = 0.f;
    f32x4 gacc[4];
    const ushort* gbB = gb16 + (size_t)b * LL * LL;
#pragma unroll
    for (int r = 0; r < 4; ++r) {
        ushort4 g4 = *(const ushort4*)(gbB + (size_t)(q0 + qrow + r) * LL + k0 + l16 * 4);
        gacc[0][r] = b2f(g4.x);
        gacc[1][r] = b2f(g4.y);
        gacc[2][r] = b2f(g4.z);
        gacc[3][r] = b2f(g4.w);
    }
    bool diag = (kt == qt);
    stage_tile(Q16 + ((size_t)(b * 16) * LL + q0) * 64, 64, Qs0, tid);
    stage_tile(K16 + ((size_t)(b * 16) * LL + k0) * 64, 64, Ks0, tid);
    __syncthreads();

#define AW_PHASE(QC, KC, QN, KN, H) do {                                          \
    if ((H) < 15) {                                                               \
        stage_tile(Q16 + ((size_t)(b * 16 + (H) + 1) * LL + q0) * 64, 64, (QN), tid); \
        stage_tile(K16 + ((size_t)(b * 16 + (H) + 1) * LL + k0) * 64, 64, (KN), tid); \
    }                                                                             \
    short8 qf_[2];                                                                \
    _Pragma("unroll")                                                             \
    for (int ks = 0; ks < 2; ++ks)                                                \
        qf_[ks] = *(const short8*)((QC) + SWZC(wid * 16 + l16, ks * 4 + quad));   \
    float mS_[4], li_[4];                                                         \
    {                                                                             \
        const float* sp_ = stats + ((size_t)(b * 16 + (H)) * LL + q0 + qrow) * 2; \
        _Pragma("unroll")                                                         \
        for (int r = 0; r < 4; ++r) {                                             \
            mS_[r] = sp_[r * 2] * SCL;                                            \
            li_[r] = 1.0f / sp_[r * 2 + 1];                                       \
        }                                                                         \
    }                                                                             \
    f32x4 sf_[4];                                                                 \
    _Pragma("unroll")                                                             \
    for (int nt = 0; nt < 4; ++nt) sf_[nt] = gacc[nt];                            \
    __builtin_amdgcn_s_setprio(1);                                                \
    _Pragma("unroll")                                                             \
    for (int ks = 0; ks < 2; ++ks)                                                \
        _Pragma("unroll")                                                         \
        for (int nt = 0; nt < 4; ++nt) {                                          \
            short8 kf_ = *(const short8*)((KC) + SWZC(nt * 16 + l16, ks * 4 + quad)); \
            sf_[nt] = __builtin_amdgcn_mfma_f32_16x16x32_bf16(qf_[ks], kf_, sf_[nt], 0, 0, 0); \
        }                                                                         \
    __builtin_amdgcn_s_setprio(0);                                                \
    _Pragma("unroll")                                                             \
    for (int nt = 0; nt < 4; ++nt)                                                \
        _Pragma("unroll")                                                         \
        for (int r = 0; r < 4; ++r) {                                             \
            int row_ = qrow + r;                                                  \
            if (!diag || (nt * 16 + l16 <= row_))                                 \
                acc[nt][r] += __builtin_amdgcn_exp2f(fmaf(sf_[nt][r], SCL, -mS_[r])) * li_[r]; \
        }                                                                         \
    __syncthreads();                                                              \
} while (0)

    for (int h = 0; h < NHH; h += 2) {
        AW_PHASE(Qs0, Ks0, Qs1, Ks1, h);
        AW_PHASE(Qs1, Ks1, Qs0, Ks0, h + 1);
    }
#undef AW_PHASE

#pragma unroll
    for (int r = 0; r < 4; ++r) {
        float* op = aw + ((size_t)(b * LL) + q0 + qrow + r) * LL + k0 + l16;
#pragma unroll
        for (int nt = 0; nt < 4; ++nt)
            op[nt * 16] = acc[nt][r] * 0.0625f;
    }
}

// ---------------- adv = -nu*U*G, layernorm -> adv_n (bf16 out) ----------------
__global__ __launch_bounds__(256) void adv_ln_kernel(
        const float* __restrict__ U, const float* __restrict__ G,
        const float* __restrict__ nub, const float* __restrict__ lnw,
        const float* __restrict__ lnb, ushort* __restrict__ out) {
    int row = blockIdx.x, tid = threadIdx.x;
    size_t base = (size_t)row * DD + tid * 4;
    float4 u4 = *(const float4*)&U[base];
    float4 g4 = *(const float4*)&G[base];
    float nu = nub[row];
    float a[4];
    a[0] = -nu * u4.x * g4.x;
    a[1] = -nu * u4.y * g4.y;
    a[2] = -nu * u4.z * g4.z;
    a[3] = -nu * u4.w * g4.w;
    float ts = a[0] + a[1] + a[2] + a[3];
    float tq = a[0] * a[0] + a[1] * a[1] + a[2] * a[2] + a[3] * a[3];
    for (int off = 32; off; off >>= 1) {
        ts += __shfl_down(ts, off);
        tq += __shfl_down(tq, off);
    }
    __shared__ float r1[4], r2[4];
    if ((tid & 63) == 0) { r1[tid >> 6] = ts; r2[tid >> 6] = tq; }
    __syncthreads();
    __shared__ float s_mu, s_rs;
    if (tid == 0) {
        float S  = r1[0] + r1[1] + r1[2] + r1[3];
        float Qq = r2[0] + r2[1] + r2[2] + r2[3];
        float mu = S * (1.0f / 1024.f);
        float var = Qq * (1.0f / 1024.f) - mu * mu;
        s_mu = mu;
        s_rs = rsqrtf(var + 1e-5f);
    }
    __syncthreads();
    float mu = s_mu, rs = s_rs;
    float4 w4 = *(const float4*)&lnw[tid * 4];
    float4 b4 = *(const float4*)&lnb[tid * 4];
    ushort4 ov;
    ov.x = f2b((a[0] - mu) * rs * w4.x + b4.x);
    ov.y = f2b((a[1] - mu) * rs * w4.y + b4.y);
    ov.z = f2b((a[2] - mu) * rs * w4.z + b4.z);
    ov.w = f2b((a[3] - mu) * rs * w4.w + b4.w);
    *(ushort4*)&out[base] = ov;
}

// ---------------- final residual combine (sums split-K partials + Cb) ----------------
__global__ void final_kernel(const float* __restrict__ z, const float* __restrict__ ao,
                             const float* __restrict__ p0, const float* __restrict__ p1,
                             const float* __restrict__ Cb, float* __restrict__ out) {
    size_t i = ((size_t)blockIdx.x * 256 + threadIdx.x) * 4;
    int col = (int)(i & (DD - 1));
    float4 z4 = *(const float4*)&z[i];
    float4 a4 = *(const float4*)&ao[i];
    float4 m0 = *(const float4*)&p0[i];
    float4 m1 = *(const float4*)&p1[i];
    float4 cb = *(const float4*)&Cb[col];
    float4 o;
    o.x = z4.x + 0.42f * a4.x + 1.07f * (m0.x + m1.x + cb.x);
    o.y = z4.y + 0.42f * a4.y + 1.07f * (m0.y + m1.y + cb.y);
    o.z = z4.z + 0.42f * a4.z + 1.07f * (m0.z + m1.z + cb.z);
    o.w = z4.w + 0.42f * a4.w + 1.07f * (m0.w + m1.w + cb.w);
    *(float4*)&out[i] = o;
}

extern "C" void kernel_launch(void* const* d_in, const int* in_sizes, int n_in,
                              void* d_out, int out_size, void* d_ws, size_t ws_size,
                              hipStream_t stream) {
    const float* z       = (const float*)d_in[0];
    const float* Wq      = (const float*)d_in[1];
    const float* bq      = (const float*)d_in[2];
    const float* Wk      = (const float*)d_in[3];
    const float* bk      = (const float*)d_in[4];
    const float* Wv      = (const float*)d_in[5];
    const float* bv      = (const float*)d_in[6];
    const float* Wcoh    = (const float*)d_in[7];
    const float* gamma   = (const float*)d_in[8];
    const float* rg_w1   = (const float*)d_in[9];
    const float* rg_b1   = (const float*)d_in[10];
    const float* rg_w2   = (const float*)d_in[11];
    const float* rg_b2   = (const float*)d_in[12];
    const float* nu_diff = (const float*)d_in[13];
    const float* nu_adv  = (const float*)d_in[14];
    const float* nu_w1   = (const float*)d_in[15];
    const float* nu_b1   = (const float*)d_in[16];
    const float* nu_w2   = (const float*)d_in[17];
    const float* nu_b2   = (const float*)d_in[18];
    const float* Wu      = (const float*)d_in[19];
    const float* bu      = (const float*)d_in[20];
    const float* Wg      = (const float*)d_in[21];
    const float* bg      = (const float*)d_in[22];
    const float* ln_w    = (const float*)d_in[23];
    const float* ln_b    = (const float*)d_in[24];
    const float* Cw      = (const float*)d_in[25];
    const float* Cb      = (const float*)d_in[26];

    float* out_z  = (float*)d_out;
    float* out_aw = out_z + (size_t)MM * DD;

    float* ws = (float*)d_ws;
    const size_t MD = (size_t)MM * DD;   // 4,194,304
    float* pool  = ws;               // poolb/VT16 in lower 8MB; transposed Wu/Wg/Cw/rg/nu upper 8MB
    float* Qb    = ws + MD;          // later U, later mlp partial 0
    float* Kb    = ws + 2 * MD;      // later G, later mlp partial 1
    float* Vb    = ws + 3 * MD;      // later Q16/K16 (bf16)
    float* gkb   = ws + 4 * MD;      // scan partials; then gk16+K16r (bf16); then attn_out
    float* gbb   = ws + 5 * MD;      // Ab(8MB) + Wb(8MB, 4 slots) + gb16(16MB)
    float* H1    = ws + 7 * MD;      // MM*256
    float* N1    = H1 + (size_t)MM * HG;
    float* gate  = N1 + (size_t)MM * HN;
    float* nub   = gate + MM;
    float* stats = nub + MM;                       // B*NH*L*2
    float* ctot  = stats + (size_t)BB * NHH * LL * 2;  // B*NCH*DD

    char* gbase  = (char*)gbb;
    ushort* Ab   = (ushort*)gbase;                               // zb / z_glu / adv_n
    ushort* Wb   = (ushort*)(gbase + (size_t)8 * 1024 * 1024);   // Wq,Wk,Wv,Wcoh transposed
    ushort* gb16 = (ushort*)(gbase + (size_t)16 * 1024 * 1024);  // gb8 bf16 (pi layout)
    ushort* PU   = (ushort*)pool + (size_t)4 * 1024 * 1024;      // pool upper 8MB: Wu,Wg,Cw,rg,nu
    ushort* WtRG = PU + (size_t)3 * 1024 * 1024;
    ushort* WtNU = WtRG + 256 * 1024;
    ushort* Q16  = (ushort*)Vb;                  // [b,h,L,64]
    ushort* K16  = (ushort*)Vb + MD;             // [b,h,L,64]
    ushort* VT16 = (ushort*)pool;                // [b,h,64,L] (lower 8MB)
    ushort* poolb = (ushort*)pool;               // [b*L,1024] bf16 (dead before VT16)
    float*  part = gkb;                          // scan partials (fp32)
    ushort* gk16 = (ushort*)gkb;                 // [b*L,1024] bf16
    ushort* K16r = (ushort*)gkb + MD;            // [b*L,1024] bf16 (pre-RoPE K)

    // 1. pool scan (also emits z bf16 into Ab)
    pool_scan1<<<dim3(NCH, 4, BB), 256, 0, stream>>>(z, part, ctot, Ab);
    pool_scan2<<<dim3(NCH, 4, BB), 256, 0, stream>>>(part, ctot, poolb);
    // 2. ALL nine weight transposes in one launch
    f2bT_all<<<dim3(32, 32, 9), 256, 0, stream>>>(Wq, Wk, Wv, Wcoh, Wu, Wg, Cw,
                                                  rg_w1, nu_w1, Wb, PU);
    // 3. fused QKV + gk GEMM (1024 blocks = 4/CU)
    gemm_mfma4<<<dim3(8, 32, 4), 256, 0, stream>>>(Ab, poolb, Wb, bq, bk, bv, Qb,
                                                   K16r, gk16);
    // 4. gates GEMM (reads rg/nu transposes from pool upper)
    gemm_gates<<<dim3(3, 32), 256, 0, stream>>>(poolb, WtRG, WtNU, rg_b1, nu_b1, H1, N1);
    // 5. gb8 (MFMA, bf16 out, pi column layout)
    gb_mfma<<<dim3(256, BB), 256, 0, stream>>>(gk16, K16r, gamma, gb16);
    // 6. fused gate/nu finisher
    gatenu_fin<<<dim3(MM), 256, 0, stream>>>(H1, N1, rg_w2, rg_b2, nu_w2, nu_b2,
                                             nu_diff, nu_adv, gate, nub);
    // 7. V^T bf16 (poolb dead -> VT16 at pool base)
    vt16_kernel<<<dim3(32, 16, BB), 256, 0, stream>>>(Vb, VT16);
    // 8. rope Q,K -> bf16 head-blocked (into Vb region)
    rope_qk_bf16<<<dim3((MM * 512) / 256), 256, 0, stream>>>(Qb, Kb, gate, Q16, K16);
    // 9. MFMA flash attention (frozen r8: 1024 blocks, 4/CU, balanced qt mapping)
    attn_flash_mfma<<<dim3(NHH, 32, BB), 256, 0, stream>>>(Q16, K16, VT16, gb16, gkb, stats);
    // 10. attn_w -> second half of d_out
    attn_w_mfma<<<dim3(1024, BB), 256, 0, stream>>>(Q16, K16, gb16, stats, out_aw);
    // 11. z_glu bf16 directly into Ab
    rope_glu_b16<<<dim3((MM * 512) / 256), 256, 0, stream>>>(z, Ab);
    // 12. fused U,G GEMM (512 blocks = 2/CU; weights from pool upper)
    gemm_mfma4<<<dim3(8, 32, 2), 256, 0, stream>>>(Ab, Ab, PU, bu, bg, bg, Qb,
                                                   nullptr, nullptr);
    // 13. adv + layernorm -> Ab (bf16, direct GEMM input)
    adv_ln_kernel<<<dim3(MM), 256, 0, stream>>>(Qb, Kb, nub, ln_w, ln_b, Ab);
    // 14. mlp partials = adv_n @ Cw (split-K=2, 512 blocks = 2/CU) -> Qb, Kb
    gemm_splitk<<<dim3(8, 32, 2), 256, 0, stream>>>(Ab, PU + (size_t)2 * 1024 * 1024,
                                                    Qb, Kb);
    // 15. final combine (adds partials + Cb)
    final_kernel<<<dim3(MD / 4 / 256), 256, 0, stream>>>(z, gkb, Qb, Kb, Cb, out_z);
}